// Round 1
// baseline (804.425 us; speedup 1.0000x reference)
//
#include <hip/hip_runtime.h>
#include <math.h>

#define C 128
#define BM 128
#define BN 128
#define BK 32

// ---------------- CSR build (sort edges by dst) ----------------

__global__ void hist_kernel(const int* __restrict__ ei, int* __restrict__ deg, int E, int ET) {
  int e = blockIdx.x * blockDim.x + threadIdx.x;
  if (e >= ET) return;
  int d = (e < E) ? ei[E + e] : (e - E);   // self loop dst = node id
  atomicAdd(&deg[d], 1);
}

__global__ void scan_kernel(const int* __restrict__ deg, int* __restrict__ row_ptr, int n) {
  __shared__ int sh[1024];
  __shared__ int carry_s;
  int tid = threadIdx.x;
  if (tid == 0) carry_s = 0;
  __syncthreads();
  for (int base = 0; base < n; base += 1024) {
    int i = base + tid;
    int v = (i < n) ? deg[i] : 0;
    sh[tid] = v;
    __syncthreads();
    for (int off = 1; off < 1024; off <<= 1) {
      int t = (tid >= off) ? sh[tid - off] : 0;
      __syncthreads();
      sh[tid] += t;
      __syncthreads();
    }
    int carry = carry_s;
    if (i < n) row_ptr[i] = carry + sh[tid] - v;   // exclusive
    __syncthreads();
    if (tid == 0) carry_s = carry + sh[1023];
    __syncthreads();
  }
  if (tid == 0) row_ptr[n] = carry_s;
}

__global__ void scatter_kernel(const int* __restrict__ ei, const int* __restrict__ row_ptr,
                               int* __restrict__ cursor, int* __restrict__ col, int E, int ET) {
  int e = blockIdx.x * blockDim.x + threadIdx.x;
  if (e >= ET) return;
  int s = (e < E) ? ei[e] : (e - E);
  int d = (e < E) ? ei[E + e] : (e - E);
  int p = atomicAdd(&cursor[d], 1);
  col[row_ptr[d] + p] = s;
}

// ---------------- f32 tiled GEMM: C[M,128] = A[M,K] @ B[K,128] (+bias, relu) ----------------

__global__ __launch_bounds__(256) void gemm_f32(
    const float* __restrict__ A, const float* __restrict__ B,
    float* __restrict__ Cout, const float* __restrict__ bias,
    int M, int K, int do_relu) {
  __shared__ float As[BK][BM + 4];   // transposed A tile, padded
  __shared__ float Bs[BK][BN];
  int tid = threadIdx.x;
  int tx = tid & 15, ty = tid >> 4;
  int m0 = blockIdx.x * BM;

  float acc[2][4][2][4];
  #pragma unroll
  for (int a = 0; a < 2; a++)
    #pragma unroll
    for (int b = 0; b < 4; b++)
      #pragma unroll
      for (int c = 0; c < 2; c++)
        #pragma unroll
        for (int d = 0; d < 4; d++) acc[a][b][c][d] = 0.f;

  int arow = tid >> 3;        // 0..31
  int af4  = (tid & 7) * 4;   // 0,4,...,28

  for (int k0 = 0; k0 < K; k0 += BK) {
    #pragma unroll
    for (int pass = 0; pass < 4; pass++) {
      int r = arow + pass * 32;
      int gm = m0 + r;
      float4 a = make_float4(0.f, 0.f, 0.f, 0.f);
      if (gm < M) a = *(const float4*)&A[(size_t)gm * K + k0 + af4];
      As[af4 + 0][r] = a.x;
      As[af4 + 1][r] = a.y;
      As[af4 + 2][r] = a.z;
      As[af4 + 3][r] = a.w;
    }
    #pragma unroll
    for (int pass = 0; pass < 4; pass++) {
      int idx = tid + pass * 256;         // float4 index in 32x128 tile
      int kk = idx >> 5;
      int nn = (idx & 31) * 4;
      *(float4*)&Bs[kk][nn] = *(const float4*)&B[(size_t)(k0 + kk) * BN + nn];
    }
    __syncthreads();
    #pragma unroll
    for (int kk = 0; kk < BK; kk++) {
      float ar[2][4], br[2][4];
      float4 t;
      t = *(const float4*)&As[kk][ty * 4];      ar[0][0]=t.x; ar[0][1]=t.y; ar[0][2]=t.z; ar[0][3]=t.w;
      t = *(const float4*)&As[kk][64 + ty * 4]; ar[1][0]=t.x; ar[1][1]=t.y; ar[1][2]=t.z; ar[1][3]=t.w;
      t = *(const float4*)&Bs[kk][tx * 4];      br[0][0]=t.x; br[0][1]=t.y; br[0][2]=t.z; br[0][3]=t.w;
      t = *(const float4*)&Bs[kk][64 + tx * 4]; br[1][0]=t.x; br[1][1]=t.y; br[1][2]=t.z; br[1][3]=t.w;
      #pragma unroll
      for (int rh = 0; rh < 2; rh++)
        #pragma unroll
        for (int ri = 0; ri < 4; ri++)
          #pragma unroll
          for (int ch = 0; ch < 2; ch++)
            #pragma unroll
            for (int ci = 0; ci < 4; ci++)
              acc[rh][ri][ch][ci] += ar[rh][ri] * br[ch][ci];
    }
    __syncthreads();
  }

  #pragma unroll
  for (int rh = 0; rh < 2; rh++)
    #pragma unroll
    for (int ri = 0; ri < 4; ri++) {
      int gm = m0 + rh * 64 + ty * 4 + ri;
      if (gm >= M) continue;
      #pragma unroll
      for (int ch = 0; ch < 2; ch++) {
        int cc = ch * 64 + tx * 4;
        float4 v = make_float4(acc[rh][ri][ch][0], acc[rh][ri][ch][1],
                               acc[rh][ri][ch][2], acc[rh][ri][ch][3]);
        if (bias) { v.x += bias[cc]; v.y += bias[cc+1]; v.z += bias[cc+2]; v.w += bias[cc+3]; }
        if (do_relu) {
          v.x = fmaxf(v.x, 0.f); v.y = fmaxf(v.y, 0.f);
          v.z = fmaxf(v.z, 0.f); v.w = fmaxf(v.w, 0.f);
        }
        *(float4*)&Cout[(size_t)gm * BN + cc] = v;
      }
    }
}

// ---------------- GATv2 edge softmax + aggregation: one wave per dst node ----------------

__global__ void gat_aggregate(const float* __restrict__ xl, const float* __restrict__ xr,
                              const int* __restrict__ row_ptr, const int* __restrict__ col,
                              const float* __restrict__ att, const float* __restrict__ bias,
                              float* __restrict__ hout, int n, int do_relu) {
  int wid = (int)((blockIdx.x * (size_t)blockDim.x + threadIdx.x) >> 6);
  int lane = threadIdx.x & 63;
  if (wid >= n) return;
  int i = wid;
  int c0 = lane * 2;
  float2 xri = *(const float2*)&xr[(size_t)i * C + c0];
  float2 av  = *(const float2*)&att[c0];
  float bv0 = bias[c0], bv1 = bias[c0 + 1];
  int beg = row_ptr[i], end = row_ptr[i + 1];
  float m = -1e30f, denom = 0.f;
  float acc0 = 0.f, acc1 = 0.f;
  for (int e = beg; e < end; e++) {
    int j = col[e];
    float2 xlj = *(const float2*)&xl[(size_t)j * C + c0];
    float z0 = xlj.x + xri.x; z0 = (z0 >= 0.f) ? z0 : 0.2f * z0;
    float z1 = xlj.y + xri.y; z1 = (z1 >= 0.f) ? z1 : 0.2f * z1;
    float part = z0 * av.x + z1 * av.y;
    #pragma unroll
    for (int off = 32; off >= 1; off >>= 1)
      part += __shfl_xor(part, off);
    float ev = part;                 // full dot over 128 channels, same in all lanes
    float mn = fmaxf(m, ev);
    float scale = expf(m - mn);      // m=-1e30 first iter -> 0
    float pe = expf(ev - mn);
    denom = denom * scale + pe;
    acc0 = acc0 * scale + pe * xlj.x;
    acc1 = acc1 * scale + pe * xlj.y;
    m = mn;
  }
  float inv = 1.f / denom;           // degree >= 1 guaranteed by self loop
  float o0 = acc0 * inv + bv0;
  float o1 = acc1 * inv + bv1;
  if (do_relu) { o0 = fmaxf(o0, 0.f); o1 = fmaxf(o1, 0.f); }
  *(float2*)&hout[(size_t)i * C + c0] = make_float2(o0, o1);
}

// ---------------- scorer ----------------

__global__ void gather_pairs(const float* __restrict__ h, const int* __restrict__ tp,
                             const int* __restrict__ fp, float4* __restrict__ out, int P2) {
  int idx = blockIdx.x * blockDim.x + threadIdx.x;   // float4 index over [2P][256/4]
  if (idx >= P2 * 64) return;
  int r = idx >> 6, c4 = idx & 63;
  int half = P2 >> 1;
  const int* pairs = (r < half) ? tp : fp;
  int rr = (r < half) ? r : r - half;
  int node = pairs[rr * 2 + (c4 >= 32 ? 1 : 0)];
  out[idx] = *(const float4*)&h[(size_t)node * C + (c4 & 31) * 4];
}

__global__ void probs_loss(const float* __restrict__ hid, const float* __restrict__ W2,
                           const float* __restrict__ b2, float* __restrict__ probs_out,
                           float* __restrict__ lossacc, int rows, int P) {
  int wid = (int)((blockIdx.x * (size_t)blockDim.x + threadIdx.x) >> 6);
  int lane = threadIdx.x & 63;
  if (wid >= rows) return;
  float2 hv = *(const float2*)&hid[(size_t)wid * C + lane * 2];
  float2 wv = *(const float2*)&W2[lane * 2];
  float part = hv.x * wv.x + hv.y * wv.y;
  #pragma unroll
  for (int off = 32; off >= 1; off >>= 1)
    part += __shfl_xor(part, off);
  if (lane == 0) {
    float s = part + b2[0];
    float p = 1.f / (1.f + expf(-s));
    probs_out[wid] = p;
    float pcl = fminf(fmaxf(p, 1e-7f), 1.f - 1e-7f);
    float term = (wid < P) ? logf(pcl) : log1pf(-pcl);
    atomicAdd(lossacc, term);
  }
}

__global__ void finalize_loss(const float* __restrict__ lossacc, float* __restrict__ out, int rows) {
  out[0] = -lossacc[0] / (float)rows;
}

// ---------------- launch ----------------

extern "C" void kernel_launch(void* const* d_in, const int* in_sizes, int n_in,
                              void* d_out, int out_size, void* d_ws, size_t ws_size,
                              hipStream_t stream) {
  const float* x    = (const float*)d_in[0];
  const int*   ei   = (const int*)d_in[1];
  const int*   tp   = (const int*)d_in[2];
  const int*   fp   = (const int*)d_in[3];
  const float* Wl   = (const float*)d_in[4];
  const float* Wr   = (const float*)d_in[5];
  const float* att  = (const float*)d_in[6];
  const float* bias = (const float*)d_in[7];
  const float* W1   = (const float*)d_in[8];
  const float* b1   = (const float*)d_in[9];
  const float* W2   = (const float*)d_in[10];
  const float* b2   = (const float*)d_in[11];

  int N  = in_sizes[0] / C;    // 50000
  int E  = in_sizes[1] / 2;    // 800000
  int P  = in_sizes[2] / 2;    // 8192
  int ET = E + N;
  int P2 = 2 * P;

  float* out       = (float*)d_out;
  float* out_pos   = out;                                  // [2P, 2C] (pos then neg)
  float* out_probs = out + (size_t)P2 * 2 * C;
  float* out_loss  = out_probs + P2;

  char* w = (char*)d_ws;
  size_t NCb = (size_t)N * C * sizeof(float);
  float* xl  = (float*)w;  w += NCb;
  float* xr  = (float*)w;  w += NCb;
  float* h1  = (float*)w;  w += NCb;
  float* hid = (float*)w;  w += (size_t)P2 * C * sizeof(float);
  int* deg     = (int*)w;  w += (size_t)N * 4;
  int* row_ptr = (int*)w;  w += (size_t)(N + 1) * 4 + 12;  // keep next aligned
  int* cursor  = (int*)w;  w += (size_t)N * 4;
  int* col     = (int*)w;  w += (size_t)ET * 4;
  float* lossacc = (float*)w;

  hipMemsetAsync(deg, 0, (size_t)N * 4, stream);
  hipMemsetAsync(cursor, 0, (size_t)N * 4, stream);
  hipMemsetAsync(lossacc, 0, 4, stream);

  const int tB = 256;
  hist_kernel<<<(ET + tB - 1) / tB, tB, 0, stream>>>(ei, deg, E, ET);
  scan_kernel<<<1, 1024, 0, stream>>>(deg, row_ptr, N);
  scatter_kernel<<<(ET + tB - 1) / tB, tB, 0, stream>>>(ei, row_ptr, cursor, col, E, ET);

  int gblk = (N + BM - 1) / BM;
  const float* h = x;
  for (int l = 0; l < 2; l++) {
    gemm_f32<<<gblk, 256, 0, stream>>>(h, Wl + (size_t)l * C * C, xl, nullptr, N, C, 0);
    gemm_f32<<<gblk, 256, 0, stream>>>(h, Wr + (size_t)l * C * C, xr, nullptr, N, C, 0);
    gat_aggregate<<<(N * 64 + tB - 1) / tB, tB, 0, stream>>>(
        xl, xr, row_ptr, col, att + (size_t)l * C, bias + (size_t)l * C, h1, N, (l == 0) ? 1 : 0);
    h = h1;
  }

  gather_pairs<<<(P2 * 64 + tB - 1) / tB, tB, 0, stream>>>(h1, tp, fp, (float4*)out_pos, P2);
  gemm_f32<<<(P2 + BM - 1) / BM, 256, 0, stream>>>(out_pos, W1, hid, b1, P2, 2 * C, 1);
  probs_loss<<<(P2 * 64 + tB - 1) / tB, tB, 0, stream>>>(hid, W2, b2, out_probs, lossacc, P2, P);
  finalize_loss<<<1, 1, 0, stream>>>(lossacc, out_loss, P2);
}

// Round 2
// 519.802 us; speedup vs baseline: 1.5476x; 1.5476x over previous
//
#include <hip/hip_runtime.h>
#include <math.h>

#define C 128
#define BM 128
#define BN 128
#define BK 32
#define SCAN_B 1024

// ---------------- CSR build (sort edges by dst) ----------------

__global__ void hist_kernel(const int* __restrict__ ei, int* __restrict__ deg, int E, int ET) {
  int e = blockIdx.x * blockDim.x + threadIdx.x;
  if (e >= ET) return;
  int d = (e < E) ? ei[E + e] : (e - E);   // self loop dst = node id
  atomicAdd(&deg[d], 1);
}

// exclusive scan, stage 1: per-block scan + block sums
__global__ void scan_block(const int* __restrict__ deg, int* __restrict__ row_ptr,
                           int* __restrict__ bsums, int n) {
  __shared__ int sh[SCAN_B];
  int tid = threadIdx.x;
  int i = blockIdx.x * SCAN_B + tid;
  int v = (i < n) ? deg[i] : 0;
  sh[tid] = v;
  __syncthreads();
  #pragma unroll
  for (int off = 1; off < SCAN_B; off <<= 1) {
    int t = (tid >= off) ? sh[tid - off] : 0;
    __syncthreads();
    sh[tid] += t;
    __syncthreads();
  }
  if (i < n) row_ptr[i] = sh[tid] - v;          // block-local exclusive
  if (tid == SCAN_B - 1) bsums[blockIdx.x] = sh[tid];
}

// stage 2: exclusive scan of block sums (nb <= 64, one wave)
__global__ void scan_sums(int* __restrict__ bsums, int nb) {
  int lane = threadIdx.x;
  int v = (lane < nb) ? bsums[lane] : 0;
  int orig = v;
  #pragma unroll
  for (int off = 1; off < 64; off <<= 1) {
    int t = __shfl_up(v, off);
    if (lane >= off) v += t;
  }
  if (lane < nb) bsums[lane] = v - orig;        // exclusive
  if (lane == 63) bsums[nb] = v;                // total
}

// stage 3: add block offsets
__global__ void scan_add(int* __restrict__ row_ptr, const int* __restrict__ bsums, int n, int nb) {
  int i = blockIdx.x * blockDim.x + threadIdx.x;
  if (i < n) row_ptr[i] += bsums[i >> 10];
  if (i == 0) row_ptr[n] = bsums[nb];
}

__global__ void scatter_kernel(const int* __restrict__ ei, const int* __restrict__ row_ptr,
                               int* __restrict__ cursor, int* __restrict__ col, int E, int ET) {
  int e = blockIdx.x * blockDim.x + threadIdx.x;
  if (e >= ET) return;
  int s = (e < E) ? ei[e] : (e - E);
  int d = (e < E) ? ei[E + e] : (e - E);
  int p = atomicAdd(&cursor[d], 1);
  col[row_ptr[d] + p] = s;
}

// ---------------- f32 tiled GEMM: C[M,128] = A[M,K] @ B[K,128] (+bias, relu) ----------------

__global__ __launch_bounds__(256) void gemm_f32(
    const float* __restrict__ A, const float* __restrict__ B,
    float* __restrict__ Cout, const float* __restrict__ bias,
    int M, int K, int do_relu) {
  __shared__ float As[BK][BM + 4];   // transposed A tile, padded
  __shared__ float Bs[BK][BN];
  int tid = threadIdx.x;
  int tx = tid & 15, ty = tid >> 4;
  int m0 = blockIdx.x * BM;

  float acc[2][4][2][4];
  #pragma unroll
  for (int a = 0; a < 2; a++)
    #pragma unroll
    for (int b = 0; b < 4; b++)
      #pragma unroll
      for (int c = 0; c < 2; c++)
        #pragma unroll
        for (int d = 0; d < 4; d++) acc[a][b][c][d] = 0.f;

  int arow = tid >> 3;        // 0..31
  int af4  = (tid & 7) * 4;   // 0,4,...,28

  for (int k0 = 0; k0 < K; k0 += BK) {
    #pragma unroll
    for (int pass = 0; pass < 4; pass++) {
      int r = arow + pass * 32;
      int gm = m0 + r;
      float4 a = make_float4(0.f, 0.f, 0.f, 0.f);
      if (gm < M) a = *(const float4*)&A[(size_t)gm * K + k0 + af4];
      As[af4 + 0][r] = a.x;
      As[af4 + 1][r] = a.y;
      As[af4 + 2][r] = a.z;
      As[af4 + 3][r] = a.w;
    }
    #pragma unroll
    for (int pass = 0; pass < 4; pass++) {
      int idx = tid + pass * 256;         // float4 index in 32x128 tile
      int kk = idx >> 5;
      int nn = (idx & 31) * 4;
      *(float4*)&Bs[kk][nn] = *(const float4*)&B[(size_t)(k0 + kk) * BN + nn];
    }
    __syncthreads();
    #pragma unroll
    for (int kk = 0; kk < BK; kk++) {
      float ar[2][4], br[2][4];
      float4 t;
      t = *(const float4*)&As[kk][ty * 4];      ar[0][0]=t.x; ar[0][1]=t.y; ar[0][2]=t.z; ar[0][3]=t.w;
      t = *(const float4*)&As[kk][64 + ty * 4]; ar[1][0]=t.x; ar[1][1]=t.y; ar[1][2]=t.z; ar[1][3]=t.w;
      t = *(const float4*)&Bs[kk][tx * 4];      br[0][0]=t.x; br[0][1]=t.y; br[0][2]=t.z; br[0][3]=t.w;
      t = *(const float4*)&Bs[kk][64 + tx * 4]; br[1][0]=t.x; br[1][1]=t.y; br[1][2]=t.z; br[1][3]=t.w;
      #pragma unroll
      for (int rh = 0; rh < 2; rh++)
        #pragma unroll
        for (int ri = 0; ri < 4; ri++)
          #pragma unroll
          for (int ch = 0; ch < 2; ch++)
            #pragma unroll
            for (int ci = 0; ci < 4; ci++)
              acc[rh][ri][ch][ci] += ar[rh][ri] * br[ch][ci];
    }
    __syncthreads();
  }

  #pragma unroll
  for (int rh = 0; rh < 2; rh++)
    #pragma unroll
    for (int ri = 0; ri < 4; ri++) {
      int gm = m0 + rh * 64 + ty * 4 + ri;
      if (gm >= M) continue;
      #pragma unroll
      for (int ch = 0; ch < 2; ch++) {
        int cc = ch * 64 + tx * 4;
        float4 v = make_float4(acc[rh][ri][ch][0], acc[rh][ri][ch][1],
                               acc[rh][ri][ch][2], acc[rh][ri][ch][3]);
        if (bias) { v.x += bias[cc]; v.y += bias[cc+1]; v.z += bias[cc+2]; v.w += bias[cc+3]; }
        if (do_relu) {
          v.x = fmaxf(v.x, 0.f); v.y = fmaxf(v.y, 0.f);
          v.z = fmaxf(v.z, 0.f); v.w = fmaxf(v.w, 0.f);
        }
        *(float4*)&Cout[(size_t)gm * BN + cc] = v;
      }
    }
}

// ---------------- GATv2 edge softmax + aggregation: one wave per dst node ----------------

__global__ void gat_aggregate(const float* __restrict__ xl, const float* __restrict__ xr,
                              const int* __restrict__ row_ptr, const int* __restrict__ col,
                              const float* __restrict__ att, const float* __restrict__ bias,
                              float* __restrict__ hout, int n, int do_relu) {
  int wid = (int)((blockIdx.x * (size_t)blockDim.x + threadIdx.x) >> 6);
  int lane = threadIdx.x & 63;
  if (wid >= n) return;
  int i = wid;
  int c0 = lane * 2;
  float2 xri = *(const float2*)&xr[(size_t)i * C + c0];
  float2 av  = *(const float2*)&att[c0];
  float bv0 = bias[c0], bv1 = bias[c0 + 1];
  int beg = row_ptr[i], end = row_ptr[i + 1];
  float m = -1e30f, denom = 0.f;
  float acc0 = 0.f, acc1 = 0.f;
  for (int e = beg; e < end; e++) {
    int j = col[e];
    float2 xlj = *(const float2*)&xl[(size_t)j * C + c0];
    float z0 = xlj.x + xri.x; z0 = (z0 >= 0.f) ? z0 : 0.2f * z0;
    float z1 = xlj.y + xri.y; z1 = (z1 >= 0.f) ? z1 : 0.2f * z1;
    float part = z0 * av.x + z1 * av.y;
    #pragma unroll
    for (int off = 32; off >= 1; off >>= 1)
      part += __shfl_xor(part, off);
    float ev = part;                 // full dot over 128 channels, same in all lanes
    float mn = fmaxf(m, ev);
    float scale = expf(m - mn);      // m=-1e30 first iter -> 0
    float pe = expf(ev - mn);
    denom = denom * scale + pe;
    acc0 = acc0 * scale + pe * xlj.x;
    acc1 = acc1 * scale + pe * xlj.y;
    m = mn;
  }
  float inv = 1.f / denom;           // degree >= 1 guaranteed by self loop
  float o0 = acc0 * inv + bv0;
  float o1 = acc1 * inv + bv1;
  if (do_relu) { o0 = fmaxf(o0, 0.f); o1 = fmaxf(o1, 0.f); }
  *(float2*)&hout[(size_t)i * C + c0] = make_float2(o0, o1);
}

// ---------------- scorer ----------------

__global__ void gather_pairs(const float* __restrict__ h, const int* __restrict__ tp,
                             const int* __restrict__ fp, float4* __restrict__ out, int P2) {
  int idx = blockIdx.x * blockDim.x + threadIdx.x;   // float4 index over [2P][256/4]
  if (idx >= P2 * 64) return;
  int r = idx >> 6, c4 = idx & 63;
  int half = P2 >> 1;
  const int* pairs = (r < half) ? tp : fp;
  int rr = (r < half) ? r : r - half;
  int node = pairs[rr * 2 + (c4 >= 32 ? 1 : 0)];
  out[idx] = *(const float4*)&h[(size_t)node * C + (c4 & 31) * 4];
}

// thread-per-row dot + block-level loss reduction (one atomic per block)
__global__ __launch_bounds__(256) void probs_loss(
    const float* __restrict__ hid, const float* __restrict__ W2,
    const float* __restrict__ b2, float* __restrict__ probs_out,
    float* __restrict__ lossacc, int rows, int P) {
  __shared__ float red[256];
  int tid = threadIdx.x;
  int r = blockIdx.x * blockDim.x + tid;
  float term = 0.f;
  if (r < rows) {
    const float4* hp = (const float4*)&hid[(size_t)r * C];
    const float4* wp = (const float4*)W2;
    float s = 0.f;
    #pragma unroll
    for (int i = 0; i < 32; i++) {
      float4 h4 = hp[i], w4 = wp[i];
      s += h4.x * w4.x + h4.y * w4.y + h4.z * w4.z + h4.w * w4.w;
    }
    s += b2[0];
    float p = 1.f / (1.f + expf(-s));
    probs_out[r] = p;
    float pcl = fminf(fmaxf(p, 1e-7f), 1.f - 1e-7f);
    term = (r < P) ? logf(pcl) : log1pf(-pcl);
  }
  red[tid] = term;
  __syncthreads();
  #pragma unroll
  for (int off = 128; off >= 1; off >>= 1) {
    if (tid < off) red[tid] += red[tid + off];
    __syncthreads();
  }
  if (tid == 0) atomicAdd(lossacc, red[0]);
}

__global__ void finalize_loss(const float* __restrict__ lossacc, float* __restrict__ out, int rows) {
  out[0] = -lossacc[0] / (float)rows;
}

// ---------------- launch ----------------

extern "C" void kernel_launch(void* const* d_in, const int* in_sizes, int n_in,
                              void* d_out, int out_size, void* d_ws, size_t ws_size,
                              hipStream_t stream) {
  const float* x    = (const float*)d_in[0];
  const int*   ei   = (const int*)d_in[1];
  const int*   tp   = (const int*)d_in[2];
  const int*   fp   = (const int*)d_in[3];
  const float* Wl   = (const float*)d_in[4];
  const float* Wr   = (const float*)d_in[5];
  const float* att  = (const float*)d_in[6];
  const float* bias = (const float*)d_in[7];
  const float* W1   = (const float*)d_in[8];
  const float* b1   = (const float*)d_in[9];
  const float* W2   = (const float*)d_in[10];
  const float* b2   = (const float*)d_in[11];

  int N  = in_sizes[0] / C;    // 50000
  int E  = in_sizes[1] / 2;    // 800000
  int P  = in_sizes[2] / 2;    // 8192
  int ET = E + N;
  int P2 = 2 * P;
  int nb = (N + SCAN_B - 1) / SCAN_B;   // scan blocks (49)

  float* out       = (float*)d_out;
  float* out_pos   = out;                                  // [2P, 2C] (pos then neg)
  float* out_probs = out + (size_t)P2 * 2 * C;
  float* out_loss  = out_probs + P2;

  char* w = (char*)d_ws;
  size_t NCb = (size_t)N * C * sizeof(float);
  float* xl  = (float*)w;  w += NCb;
  float* xr  = (float*)w;  w += NCb;
  float* h1  = (float*)w;  w += NCb;
  float* hid = (float*)w;  w += (size_t)P2 * C * sizeof(float);
  int* deg     = (int*)w;  w += (size_t)N * 4;
  int* row_ptr = (int*)w;  w += (size_t)(N + 1) * 4 + 12;  // keep next aligned
  int* cursor  = (int*)w;  w += (size_t)N * 4;
  int* col     = (int*)w;  w += (size_t)ET * 4;
  int* bsums   = (int*)w;  w += (size_t)(nb + 1) * 4;
  float* lossacc = (float*)w;

  hipMemsetAsync(deg, 0, (size_t)N * 4, stream);
  hipMemsetAsync(cursor, 0, (size_t)N * 4, stream);
  hipMemsetAsync(lossacc, 0, 4, stream);

  const int tB = 256;
  hist_kernel<<<(ET + tB - 1) / tB, tB, 0, stream>>>(ei, deg, E, ET);
  scan_block<<<nb, SCAN_B, 0, stream>>>(deg, row_ptr, bsums, N);
  scan_sums<<<1, 64, 0, stream>>>(bsums, nb);
  scan_add<<<(N + SCAN_B - 1) / SCAN_B, SCAN_B, 0, stream>>>(row_ptr, bsums, N, nb);
  scatter_kernel<<<(ET + tB - 1) / tB, tB, 0, stream>>>(ei, row_ptr, cursor, col, E, ET);

  int gblk = (N + BM - 1) / BM;
  const float* h = x;
  for (int l = 0; l < 2; l++) {
    gemm_f32<<<gblk, 256, 0, stream>>>(h, Wl + (size_t)l * C * C, xl, nullptr, N, C, 0);
    gemm_f32<<<gblk, 256, 0, stream>>>(h, Wr + (size_t)l * C * C, xr, nullptr, N, C, 0);
    gat_aggregate<<<(N * 64 + tB - 1) / tB, tB, 0, stream>>>(
        xl, xr, row_ptr, col, att + (size_t)l * C, bias + (size_t)l * C, h1, N, (l == 0) ? 1 : 0);
    h = h1;
  }

  gather_pairs<<<(P2 * 64 + tB - 1) / tB, tB, 0, stream>>>(h1, tp, fp, (float4*)out_pos, P2);
  gemm_f32<<<(P2 + BM - 1) / BM, 256, 0, stream>>>(out_pos, W1, hid, b1, P2, 2 * C, 1);
  probs_loss<<<(P2 + tB - 1) / tB, tB, 0, stream>>>(hid, W2, b2, out_probs, lossacc, P2, P);
  finalize_loss<<<1, 1, 0, stream>>>(lossacc, out_loss, P2);
}

// Round 3
// 417.825 us; speedup vs baseline: 1.9253x; 1.2441x over previous
//
#include <hip/hip_runtime.h>
#include <math.h>

#define C 128
#define BM 128
#define BN 128
#define BK 32
#define SCAN_B 1024

typedef unsigned short ushort_t;

__device__ __forceinline__ ushort_t f2bf(float x) {
  unsigned u = __float_as_uint(x);
  unsigned r = (u + 0x7FFFu + ((u >> 16) & 1u)) >> 16;
  return (ushort_t)r;
}
__device__ __forceinline__ float bf_lo(unsigned u) { return __uint_as_float(u << 16); }
__device__ __forceinline__ float bf_hi(unsigned u) { return __uint_as_float(u & 0xFFFF0000u); }

// ---------------- CSR build (sort edges by dst) ----------------

__global__ void hist_kernel(const int* __restrict__ ei, int* __restrict__ deg, int E, int ET) {
  int e = blockIdx.x * blockDim.x + threadIdx.x;
  if (e >= ET) return;
  int d = (e < E) ? ei[E + e] : (e - E);   // self loop dst = node id
  atomicAdd(&deg[d], 1);
}

__global__ void scan_block(const int* __restrict__ deg, int* __restrict__ row_ptr,
                           int* __restrict__ bsums, int n) {
  __shared__ int sh[SCAN_B];
  int tid = threadIdx.x;
  int i = blockIdx.x * SCAN_B + tid;
  int v = (i < n) ? deg[i] : 0;
  sh[tid] = v;
  __syncthreads();
  #pragma unroll
  for (int off = 1; off < SCAN_B; off <<= 1) {
    int t = (tid >= off) ? sh[tid - off] : 0;
    __syncthreads();
    sh[tid] += t;
    __syncthreads();
  }
  if (i < n) row_ptr[i] = sh[tid] - v;          // block-local exclusive
  if (tid == SCAN_B - 1) bsums[blockIdx.x] = sh[tid];
}

__global__ void scan_sums(int* __restrict__ bsums, int nb) {
  int lane = threadIdx.x;
  int v = (lane < nb) ? bsums[lane] : 0;
  int orig = v;
  #pragma unroll
  for (int off = 1; off < 64; off <<= 1) {
    int t = __shfl_up(v, off);
    if (lane >= off) v += t;
  }
  if (lane < nb) bsums[lane] = v - orig;        // exclusive
  if (lane == 63) bsums[nb] = v;                // total
}

__global__ void scan_add(int* __restrict__ row_ptr, const int* __restrict__ bsums, int n, int nb) {
  int i = blockIdx.x * blockDim.x + threadIdx.x;
  if (i < n) row_ptr[i] += bsums[i >> 10];
  if (i == 0) row_ptr[n] = bsums[nb];
}

__global__ void scatter_kernel(const int* __restrict__ ei, const int* __restrict__ row_ptr,
                               int* __restrict__ cursor, int* __restrict__ col, int E, int ET) {
  int e = blockIdx.x * blockDim.x + threadIdx.x;
  if (e >= ET) return;
  int s = (e < E) ? ei[e] : (e - E);
  int d = (e < E) ? ei[E + e] : (e - E);
  int p = atomicAdd(&cursor[d], 1);
  col[row_ptr[d] + p] = s;
}

// ---------------- f32 tiled GEMM: C[M,128] = A[M,K] @ B[K,128] (+bias, relu) ----------------
// If Cbf != nullptr, output is written as bf16 (rn) instead of f32.

__global__ __launch_bounds__(256) void gemm_f32(
    const float* __restrict__ A, const float* __restrict__ B,
    float* __restrict__ Cout, ushort_t* __restrict__ Cbf,
    const float* __restrict__ bias, int M, int K, int do_relu) {
  __shared__ float As[BK][BM + 4];   // transposed A tile, padded
  __shared__ float Bs[BK][BN];
  int tid = threadIdx.x;
  int tx = tid & 15, ty = tid >> 4;
  int m0 = blockIdx.x * BM;

  float acc[2][4][2][4];
  #pragma unroll
  for (int a = 0; a < 2; a++)
    #pragma unroll
    for (int b = 0; b < 4; b++)
      #pragma unroll
      for (int c = 0; c < 2; c++)
        #pragma unroll
        for (int d = 0; d < 4; d++) acc[a][b][c][d] = 0.f;

  int arow = tid >> 3;        // 0..31
  int af4  = (tid & 7) * 4;   // 0,4,...,28

  for (int k0 = 0; k0 < K; k0 += BK) {
    #pragma unroll
    for (int pass = 0; pass < 4; pass++) {
      int r = arow + pass * 32;
      int gm = m0 + r;
      float4 a = make_float4(0.f, 0.f, 0.f, 0.f);
      if (gm < M) a = *(const float4*)&A[(size_t)gm * K + k0 + af4];
      As[af4 + 0][r] = a.x;
      As[af4 + 1][r] = a.y;
      As[af4 + 2][r] = a.z;
      As[af4 + 3][r] = a.w;
    }
    #pragma unroll
    for (int pass = 0; pass < 4; pass++) {
      int idx = tid + pass * 256;         // float4 index in 32x128 tile
      int kk = idx >> 5;
      int nn = (idx & 31) * 4;
      *(float4*)&Bs[kk][nn] = *(const float4*)&B[(size_t)(k0 + kk) * BN + nn];
    }
    __syncthreads();
    #pragma unroll
    for (int kk = 0; kk < BK; kk++) {
      float ar[2][4], br[2][4];
      float4 t;
      t = *(const float4*)&As[kk][ty * 4];      ar[0][0]=t.x; ar[0][1]=t.y; ar[0][2]=t.z; ar[0][3]=t.w;
      t = *(const float4*)&As[kk][64 + ty * 4]; ar[1][0]=t.x; ar[1][1]=t.y; ar[1][2]=t.z; ar[1][3]=t.w;
      t = *(const float4*)&Bs[kk][tx * 4];      br[0][0]=t.x; br[0][1]=t.y; br[0][2]=t.z; br[0][3]=t.w;
      t = *(const float4*)&Bs[kk][64 + tx * 4]; br[1][0]=t.x; br[1][1]=t.y; br[1][2]=t.z; br[1][3]=t.w;
      #pragma unroll
      for (int rh = 0; rh < 2; rh++)
        #pragma unroll
        for (int ri = 0; ri < 4; ri++)
          #pragma unroll
          for (int ch = 0; ch < 2; ch++)
            #pragma unroll
            for (int ci = 0; ci < 4; ci++)
              acc[rh][ri][ch][ci] += ar[rh][ri] * br[ch][ci];
    }
    __syncthreads();
  }

  #pragma unroll
  for (int rh = 0; rh < 2; rh++)
    #pragma unroll
    for (int ri = 0; ri < 4; ri++) {
      int gm = m0 + rh * 64 + ty * 4 + ri;
      if (gm >= M) continue;
      #pragma unroll
      for (int ch = 0; ch < 2; ch++) {
        int cc = ch * 64 + tx * 4;
        float4 v = make_float4(acc[rh][ri][ch][0], acc[rh][ri][ch][1],
                               acc[rh][ri][ch][2], acc[rh][ri][ch][3]);
        if (bias) { v.x += bias[cc]; v.y += bias[cc+1]; v.z += bias[cc+2]; v.w += bias[cc+3]; }
        if (do_relu) {
          v.x = fmaxf(v.x, 0.f); v.y = fmaxf(v.y, 0.f);
          v.z = fmaxf(v.z, 0.f); v.w = fmaxf(v.w, 0.f);
        }
        if (Cbf) {
          ushort4 s;
          s.x = f2bf(v.x); s.y = f2bf(v.y); s.z = f2bf(v.z); s.w = f2bf(v.w);
          *(ushort4*)&Cbf[(size_t)gm * BN + cc] = s;
        } else {
          *(float4*)&Cout[(size_t)gm * BN + cc] = v;
        }
      }
    }
}

// ---------------- GATv2 edge softmax + aggregation: one wave per dst node ----------------
// xl is bf16 [N,C]; one-pass softmax (no max subtraction -- exact same ratio in f32).

__global__ void gat_aggregate(const ushort_t* __restrict__ xl, const float* __restrict__ xr,
                              const int* __restrict__ row_ptr, const int* __restrict__ col,
                              const float* __restrict__ att, const float* __restrict__ bias,
                              float* __restrict__ hout, int n, int do_relu) {
  int wid = (int)((blockIdx.x * (size_t)blockDim.x + threadIdx.x) >> 6);
  int lane = threadIdx.x & 63;
  if (wid >= n) return;
  int i = wid;
  int c0 = lane * 2;
  float2 xri = *(const float2*)&xr[(size_t)i * C + c0];
  float2 av  = *(const float2*)&att[c0];
  int beg = row_ptr[i], end = row_ptr[i + 1];
  float denom = 0.f, acc0 = 0.f, acc1 = 0.f;

  for (int base = beg; base < end; base += 64) {
    int idx = base + lane;
    int jv = (idx < end) ? col[idx] : 0;
    int cnt = min(64, end - base);
    for (int t = 0; t < cnt; t += 2) {
      bool has1 = (t + 1) < cnt;
      int t1 = has1 ? (t + 1) : t;
      int j0 = __shfl(jv, t);
      int j1 = __shfl(jv, t1);
      unsigned u0 = *(const unsigned*)&xl[(size_t)j0 * C + c0];
      unsigned u1 = *(const unsigned*)&xl[(size_t)j1 * C + c0];
      float a0x = bf_lo(u0), a0y = bf_hi(u0);
      float a1x = bf_lo(u1), a1y = bf_hi(u1);
      float z;
      z = a0x + xri.x; z = fmaxf(z, 0.2f * z); float p0 = z * av.x;
      z = a0y + xri.y; z = fmaxf(z, 0.2f * z); p0 += z * av.y;
      z = a1x + xri.x; z = fmaxf(z, 0.2f * z); float p1 = z * av.x;
      z = a1y + xri.y; z = fmaxf(z, 0.2f * z); p1 += z * av.y;
      #pragma unroll
      for (int off = 32; off >= 1; off >>= 1) {
        p0 += __shfl_xor(p0, off);
        p1 += __shfl_xor(p1, off);
      }
      float pe0 = __expf(p0);
      float pe1 = has1 ? __expf(p1) : 0.f;
      denom += pe0 + pe1;
      acc0 += pe0 * a0x + pe1 * a1x;
      acc1 += pe0 * a0y + pe1 * a1y;
    }
  }
  float inv = 1.f / denom;           // degree >= 1 guaranteed by self loop
  float o0 = acc0 * inv + bias[c0];
  float o1 = acc1 * inv + bias[c0 + 1];
  if (do_relu) { o0 = fmaxf(o0, 0.f); o1 = fmaxf(o1, 0.f); }
  *(float2*)&hout[(size_t)i * C + c0] = make_float2(o0, o1);
}

// ---------------- scorer ----------------

__global__ void gather_pairs(const float* __restrict__ h, const int* __restrict__ tp,
                             const int* __restrict__ fp, float4* __restrict__ out, int P2) {
  int idx = blockIdx.x * blockDim.x + threadIdx.x;   // float4 index over [2P][256/4]
  if (idx >= P2 * 64) return;
  int r = idx >> 6, c4 = idx & 63;
  int half = P2 >> 1;
  const int* pairs = (r < half) ? tp : fp;
  int rr = (r < half) ? r : r - half;
  int node = pairs[rr * 2 + (c4 >= 32 ? 1 : 0)];
  out[idx] = *(const float4*)&h[(size_t)node * C + (c4 & 31) * 4];
}

// thread-per-row dot + block-level loss reduction (one atomic per block)
__global__ __launch_bounds__(256) void probs_loss(
    const float* __restrict__ hid, const float* __restrict__ W2,
    const float* __restrict__ b2, float* __restrict__ probs_out,
    float* __restrict__ lossacc, int rows, int P) {
  __shared__ float red[256];
  int tid = threadIdx.x;
  int r = blockIdx.x * blockDim.x + tid;
  float term = 0.f;
  if (r < rows) {
    const float4* hp = (const float4*)&hid[(size_t)r * C];
    const float4* wp = (const float4*)W2;
    float s = 0.f;
    #pragma unroll
    for (int i = 0; i < 32; i++) {
      float4 h4 = hp[i], w4 = wp[i];
      s += h4.x * w4.x + h4.y * w4.y + h4.z * w4.z + h4.w * w4.w;
    }
    s += b2[0];
    float p = 1.f / (1.f + expf(-s));
    probs_out[r] = p;
    float pcl = fminf(fmaxf(p, 1e-7f), 1.f - 1e-7f);
    term = (r < P) ? logf(pcl) : log1pf(-pcl);
  }
  red[tid] = term;
  __syncthreads();
  #pragma unroll
  for (int off = 128; off >= 1; off >>= 1) {
    if (tid < off) red[tid] += red[tid + off];
    __syncthreads();
  }
  if (tid == 0) atomicAdd(lossacc, red[0]);
}

__global__ void finalize_loss(const float* __restrict__ lossacc, float* __restrict__ out, int rows) {
  out[0] = -lossacc[0] / (float)rows;
}

// ---------------- launch ----------------

extern "C" void kernel_launch(void* const* d_in, const int* in_sizes, int n_in,
                              void* d_out, int out_size, void* d_ws, size_t ws_size,
                              hipStream_t stream) {
  const float* x    = (const float*)d_in[0];
  const int*   ei   = (const int*)d_in[1];
  const int*   tp   = (const int*)d_in[2];
  const int*   fp   = (const int*)d_in[3];
  const float* Wl   = (const float*)d_in[4];
  const float* Wr   = (const float*)d_in[5];
  const float* att  = (const float*)d_in[6];
  const float* bias = (const float*)d_in[7];
  const float* W1   = (const float*)d_in[8];
  const float* b1   = (const float*)d_in[9];
  const float* W2   = (const float*)d_in[10];
  const float* b2   = (const float*)d_in[11];

  int N  = in_sizes[0] / C;    // 50000
  int E  = in_sizes[1] / 2;    // 800000
  int P  = in_sizes[2] / 2;    // 8192
  int ET = E + N;
  int P2 = 2 * P;
  int nb = (N + SCAN_B - 1) / SCAN_B;   // scan blocks (49)

  float* out       = (float*)d_out;
  float* out_pos   = out;                                  // [2P, 2C] (pos then neg)
  float* out_probs = out + (size_t)P2 * 2 * C;
  float* out_loss  = out_probs + P2;

  char* w = (char*)d_ws;
  size_t NCb = (size_t)N * C * sizeof(float);
  ushort_t* xl_bf = (ushort_t*)w;  w += NCb;               // bf16, uses half; keep slot size
  float* xr  = (float*)w;  w += NCb;
  float* h1  = (float*)w;  w += NCb;
  float* hid = (float*)w;  w += (size_t)P2 * C * sizeof(float);
  int* deg     = (int*)w;  w += (size_t)N * 4;
  int* row_ptr = (int*)w;  w += (size_t)(N + 1) * 4 + 12;  // keep next aligned
  int* cursor  = (int*)w;  w += (size_t)N * 4;
  int* col     = (int*)w;  w += (size_t)ET * 4;
  int* bsums   = (int*)w;  w += (size_t)(nb + 1) * 4;
  float* lossacc = (float*)w;

  hipMemsetAsync(deg, 0, (size_t)N * 4, stream);
  hipMemsetAsync(cursor, 0, (size_t)N * 4, stream);
  hipMemsetAsync(lossacc, 0, 4, stream);

  const int tB = 256;
  hist_kernel<<<(ET + tB - 1) / tB, tB, 0, stream>>>(ei, deg, E, ET);
  scan_block<<<nb, SCAN_B, 0, stream>>>(deg, row_ptr, bsums, N);
  scan_sums<<<1, 64, 0, stream>>>(bsums, nb);
  scan_add<<<(N + SCAN_B - 1) / SCAN_B, SCAN_B, 0, stream>>>(row_ptr, bsums, N, nb);
  scatter_kernel<<<(ET + tB - 1) / tB, tB, 0, stream>>>(ei, row_ptr, cursor, col, E, ET);

  int gblk = (N + BM - 1) / BM;
  const float* h = x;
  for (int l = 0; l < 2; l++) {
    gemm_f32<<<gblk, 256, 0, stream>>>(h, Wl + (size_t)l * C * C, nullptr, xl_bf, nullptr, N, C, 0);
    gemm_f32<<<gblk, 256, 0, stream>>>(h, Wr + (size_t)l * C * C, xr, nullptr, nullptr, N, C, 0);
    gat_aggregate<<<(N * 64 + tB - 1) / tB, tB, 0, stream>>>(
        xl_bf, xr, row_ptr, col, att + (size_t)l * C, bias + (size_t)l * C, h1, N, (l == 0) ? 1 : 0);
    h = h1;
  }

  gather_pairs<<<(P2 * 64 + tB - 1) / tB, tB, 0, stream>>>(h1, tp, fp, (float4*)out_pos, P2);
  gemm_f32<<<(P2 + BM - 1) / BM, 256, 0, stream>>>(out_pos, W1, hid, nullptr, b1, P2, 2 * C, 1);
  probs_loss<<<(P2 + tB - 1) / tB, tB, 0, stream>>>(hid, W2, b2, out_probs, lossacc, P2, P);
  finalize_loss<<<1, 1, 0, stream>>>(lossacc, out_loss, P2);
}

// Round 4
// 348.734 us; speedup vs baseline: 2.3067x; 1.1981x over previous
//
#include <hip/hip_runtime.h>
#include <math.h>

#define C 128
#define SCAN_B 1024

typedef unsigned short ushort_t;
typedef short short8 __attribute__((ext_vector_type(8)));
typedef float floatx4 __attribute__((ext_vector_type(4)));

__device__ __forceinline__ ushort_t f2bf(float x) {
  unsigned u = __float_as_uint(x);
  unsigned r = (u + 0x7FFFu + ((u >> 16) & 1u)) >> 16;
  return (ushort_t)r;
}
__device__ __forceinline__ float bf_lo(unsigned u) { return __uint_as_float(u << 16); }
__device__ __forceinline__ float bf_hi(unsigned u) { return __uint_as_float(u & 0xFFFF0000u); }

// ---------------- CSR build (sort edges by dst) ----------------

__global__ void hist_kernel(const int* __restrict__ ei, int* __restrict__ deg, int E, int ET) {
  int e = blockIdx.x * blockDim.x + threadIdx.x;
  if (e >= ET) return;
  int d = (e < E) ? ei[E + e] : (e - E);   // self loop dst = node id
  atomicAdd(&deg[d], 1);
}

__global__ void scan_block(const int* __restrict__ deg, int* __restrict__ row_ptr,
                           int* __restrict__ bsums, int n) {
  __shared__ int sh[SCAN_B];
  int tid = threadIdx.x;
  int i = blockIdx.x * SCAN_B + tid;
  int v = (i < n) ? deg[i] : 0;
  sh[tid] = v;
  __syncthreads();
  #pragma unroll
  for (int off = 1; off < SCAN_B; off <<= 1) {
    int t = (tid >= off) ? sh[tid - off] : 0;
    __syncthreads();
    sh[tid] += t;
    __syncthreads();
  }
  if (i < n) row_ptr[i] = sh[tid] - v;          // block-local exclusive
  if (tid == SCAN_B - 1) bsums[blockIdx.x] = sh[tid];
}

__global__ void scan_sums(int* __restrict__ bsums, int nb) {
  int lane = threadIdx.x;
  int v = (lane < nb) ? bsums[lane] : 0;
  int orig = v;
  #pragma unroll
  for (int off = 1; off < 64; off <<= 1) {
    int t = __shfl_up(v, off);
    if (lane >= off) v += t;
  }
  if (lane < nb) bsums[lane] = v - orig;        // exclusive
  if (lane == 63) bsums[nb] = v;                // total
}

__global__ void scan_add(int* __restrict__ row_ptr, const int* __restrict__ bsums, int n, int nb) {
  int i = blockIdx.x * blockDim.x + threadIdx.x;
  if (i < n) row_ptr[i] += bsums[i >> 10];
  if (i == 0) row_ptr[n] = bsums[nb];
}

__global__ void scatter_kernel(const int* __restrict__ ei, const int* __restrict__ row_ptr,
                               int* __restrict__ cursor, int* __restrict__ col, int E, int ET) {
  int e = blockIdx.x * blockDim.x + threadIdx.x;
  if (e >= ET) return;
  int s = (e < E) ? ei[e] : (e - E);
  int d = (e < E) ? ei[E + e] : (e - E);
  int p = atomicAdd(&cursor[d], 1);
  col[row_ptr[d] + p] = s;
}

// ---------------- weight prep: transpose + bf16 ----------------
// wcat[l][n(0..255)][k]  (n<128: Wl col n; n>=128: Wr col n-128)
// w1t[n(0..127)][k(0..255)] = W1[k][n]

__global__ void prep_weights(const float* __restrict__ Wl, const float* __restrict__ Wr,
                             const float* __restrict__ W1,
                             ushort_t* __restrict__ wcat, ushort_t* __restrict__ w1t) {
  int idx = blockIdx.x * blockDim.x + threadIdx.x;
  const int NCAT = 2 * 256 * 128;
  if (idx < NCAT) {
    int l = idx >> 15;           // /32768
    int rem = idx & 32767;
    int n = rem >> 7;
    int k = rem & 127;
    float v = (n < 128) ? Wl[l * C * C + k * C + n] : Wr[l * C * C + k * C + (n - 128)];
    wcat[idx] = f2bf(v);
  } else {
    int j = idx - NCAT;          // w1t index
    if (j < 128 * 256) {
      int n = j >> 8;
      int k = j & 255;
      w1t[j] = f2bf(W1[k * C + n]);
    }
  }
}

__global__ void convert_x(const float* __restrict__ x, ushort_t* __restrict__ xb, int total4) {
  int i = blockIdx.x * blockDim.x + threadIdx.x;
  if (i >= total4) return;
  float4 v = ((const float4*)x)[i];
  ushort4 s;
  s.x = f2bf(v.x); s.y = f2bf(v.y); s.z = f2bf(v.z); s.w = f2bf(v.w);
  ((ushort4*)xb)[i] = s;
}

// ---------------- bf16 MFMA GEMM ----------------
// A bf16 [M,K] row-major; Bt bf16 [NN,K] n-major (NN = gridDim.y*128).
// Block (bx,by): rows bx*128..+128, Bt rows by*128..+128.
// Output: if outf: f32 [M,128] (+bias,+relu). else bf16 to (by==0 ? outb0 : outb1).

__global__ __launch_bounds__(256) void gemm_mfma(
    const ushort_t* __restrict__ A, const ushort_t* __restrict__ Bt,
    int M, int K,
    ushort_t* __restrict__ outb0, ushort_t* __restrict__ outb1,
    float* __restrict__ outf, const float* __restrict__ bias, int do_relu) {
  int tid = threadIdx.x;
  int wave = tid >> 6, lane = tid & 63;
  int wm = (wave >> 1) * 64, wn = (wave & 1) * 64;
  int m_base = blockIdx.x * 128 + wm;
  int lrow = lane & 15, lkg = lane >> 4;

  floatx4 acc[4][4];
  #pragma unroll
  for (int mi = 0; mi < 4; mi++)
    #pragma unroll
    for (int ni = 0; ni < 4; ni++)
      acc[mi][ni] = (floatx4){0.f, 0.f, 0.f, 0.f};

  const int ksteps = K >> 5;
  for (int ks = 0; ks < ksteps; ks++) {
    int koff = ks * 32 + lkg * 8;
    short8 af[4], bfr[4];
    #pragma unroll
    for (int mi = 0; mi < 4; mi++) {
      int gm = m_base + mi * 16 + lrow;
      gm = (gm < M) ? gm : (M - 1);
      af[mi] = *(const short8*)&A[(size_t)gm * K + koff];
    }
    #pragma unroll
    for (int ni = 0; ni < 4; ni++) {
      int gn = blockIdx.y * 128 + wn + ni * 16 + lrow;
      bfr[ni] = *(const short8*)&Bt[(size_t)gn * K + koff];
    }
    #pragma unroll
    for (int mi = 0; mi < 4; mi++)
      #pragma unroll
      for (int ni = 0; ni < 4; ni++)
        acc[mi][ni] = __builtin_amdgcn_mfma_f32_16x16x32_bf16(af[mi], bfr[ni], acc[mi][ni], 0, 0, 0);
  }

  ushort_t* outb = (blockIdx.y == 0) ? outb0 : outb1;
  #pragma unroll
  for (int mi = 0; mi < 4; mi++) {
    #pragma unroll
    for (int r = 0; r < 4; r++) {
      int gm = m_base + mi * 16 + lkg * 4 + r;
      if (gm >= M) continue;
      #pragma unroll
      for (int ni = 0; ni < 4; ni++) {
        int nl = wn + ni * 16 + lrow;         // 0..127 within this by's output
        float v = acc[mi][ni][r];
        if (outf) {
          if (bias) v += bias[nl];
          if (do_relu) v = fmaxf(v, 0.f);
          outf[(size_t)gm * 128 + nl] = v;
        } else {
          outb[(size_t)gm * 128 + nl] = f2bf(v);
        }
      }
    }
  }
}

// ---------------- GATv2 edge softmax + aggregation: one wave per dst node ----------------
// xl, xr bf16 [N,C]; one-pass softmax (exact ratio, logits are O(1)).
// Output: houtf (f32) if non-null, else houtb (bf16).

__global__ void gat_aggregate(const ushort_t* __restrict__ xl, const ushort_t* __restrict__ xr,
                              const int* __restrict__ row_ptr, const int* __restrict__ col,
                              const float* __restrict__ att, const float* __restrict__ bias,
                              float* __restrict__ houtf, ushort_t* __restrict__ houtb,
                              int n, int do_relu) {
  int wid = (int)((blockIdx.x * (size_t)blockDim.x + threadIdx.x) >> 6);
  int lane = threadIdx.x & 63;
  if (wid >= n) return;
  int i = wid;
  int c0 = lane * 2;
  unsigned uxr = *(const unsigned*)&xr[(size_t)i * C + c0];
  float xrix = bf_lo(uxr), xriy = bf_hi(uxr);
  float2 av  = *(const float2*)&att[c0];
  int beg = row_ptr[i], end = row_ptr[i + 1];
  float denom = 0.f, acc0 = 0.f, acc1 = 0.f;

  for (int base = beg; base < end; base += 64) {
    int idx = base + lane;
    int jv = (idx < end) ? col[idx] : 0;
    int cnt = min(64, end - base);
    for (int t = 0; t < cnt; t += 2) {
      bool has1 = (t + 1) < cnt;
      int t1 = has1 ? (t + 1) : t;
      int j0 = __shfl(jv, t);
      int j1 = __shfl(jv, t1);
      unsigned u0 = *(const unsigned*)&xl[(size_t)j0 * C + c0];
      unsigned u1 = *(const unsigned*)&xl[(size_t)j1 * C + c0];
      float a0x = bf_lo(u0), a0y = bf_hi(u0);
      float a1x = bf_lo(u1), a1y = bf_hi(u1);
      float z;
      z = a0x + xrix; z = fmaxf(z, 0.2f * z); float p0 = z * av.x;
      z = a0y + xriy; z = fmaxf(z, 0.2f * z); p0 += z * av.y;
      z = a1x + xrix; z = fmaxf(z, 0.2f * z); float p1 = z * av.x;
      z = a1y + xriy; z = fmaxf(z, 0.2f * z); p1 += z * av.y;
      #pragma unroll
      for (int off = 32; off >= 1; off >>= 1) {
        p0 += __shfl_xor(p0, off);
        p1 += __shfl_xor(p1, off);
      }
      float pe0 = __expf(p0);
      float pe1 = has1 ? __expf(p1) : 0.f;
      denom += pe0 + pe1;
      acc0 += pe0 * a0x + pe1 * a1x;
      acc1 += pe0 * a0y + pe1 * a1y;
    }
  }
  float inv = 1.f / denom;           // degree >= 1 guaranteed by self loop
  float o0 = acc0 * inv + bias[c0];
  float o1 = acc1 * inv + bias[c0 + 1];
  if (do_relu) { o0 = fmaxf(o0, 0.f); o1 = fmaxf(o1, 0.f); }
  if (houtf) {
    *(float2*)&houtf[(size_t)i * C + c0] = make_float2(o0, o1);
  } else {
    unsigned pk = (unsigned)f2bf(o0) | ((unsigned)f2bf(o1) << 16);
    *(unsigned*)&houtb[(size_t)i * C + c0] = pk;
  }
}

// ---------------- scorer ----------------

// writes f32 concat rows to d_out AND bf16 copy for the MFMA scorer GEMM
__global__ void gather_pairs(const float* __restrict__ h, const int* __restrict__ tp,
                             const int* __restrict__ fp, float4* __restrict__ out,
                             ushort_t* __restrict__ outbf, int P2) {
  int idx = blockIdx.x * blockDim.x + threadIdx.x;   // float4 index over [2P][256/4]
  if (idx >= P2 * 64) return;
  int r = idx >> 6, c4 = idx & 63;
  int half = P2 >> 1;
  const int* pairs = (r < half) ? tp : fp;
  int rr = (r < half) ? r : r - half;
  int node = pairs[rr * 2 + (c4 >= 32 ? 1 : 0)];
  float4 v = *(const float4*)&h[(size_t)node * C + (c4 & 31) * 4];
  out[idx] = v;
  ushort4 s;
  s.x = f2bf(v.x); s.y = f2bf(v.y); s.z = f2bf(v.z); s.w = f2bf(v.w);
  *(ushort4*)&outbf[(size_t)idx * 4] = s;
}

// thread-per-row dot + block-level loss reduction (one atomic per block)
__global__ __launch_bounds__(256) void probs_loss(
    const float* __restrict__ hid, const float* __restrict__ W2,
    const float* __restrict__ b2, float* __restrict__ probs_out,
    float* __restrict__ lossacc, int rows, int P) {
  __shared__ float red[256];
  int tid = threadIdx.x;
  int r = blockIdx.x * blockDim.x + tid;
  float term = 0.f;
  if (r < rows) {
    const float4* hp = (const float4*)&hid[(size_t)r * C];
    const float4* wp = (const float4*)W2;
    float s = 0.f;
    #pragma unroll
    for (int i = 0; i < 32; i++) {
      float4 h4 = hp[i], w4 = wp[i];
      s += h4.x * w4.x + h4.y * w4.y + h4.z * w4.z + h4.w * w4.w;
    }
    s += b2[0];
    float p = 1.f / (1.f + expf(-s));
    probs_out[r] = p;
    float pcl = fminf(fmaxf(p, 1e-7f), 1.f - 1e-7f);
    term = (r < P) ? logf(pcl) : log1pf(-pcl);
  }
  red[tid] = term;
  __syncthreads();
  #pragma unroll
  for (int off = 128; off >= 1; off >>= 1) {
    if (tid < off) red[tid] += red[tid + off];
    __syncthreads();
  }
  if (tid == 0) atomicAdd(lossacc, red[0]);
}

__global__ void finalize_loss(const float* __restrict__ lossacc, float* __restrict__ out, int rows) {
  out[0] = -lossacc[0] / (float)rows;
}

// ---------------- launch ----------------

extern "C" void kernel_launch(void* const* d_in, const int* in_sizes, int n_in,
                              void* d_out, int out_size, void* d_ws, size_t ws_size,
                              hipStream_t stream) {
  const float* x    = (const float*)d_in[0];
  const int*   ei   = (const int*)d_in[1];
  const int*   tp   = (const int*)d_in[2];
  const int*   fp   = (const int*)d_in[3];
  const float* Wl   = (const float*)d_in[4];
  const float* Wr   = (const float*)d_in[5];
  const float* att  = (const float*)d_in[6];
  const float* bias = (const float*)d_in[7];
  const float* W1   = (const float*)d_in[8];
  const float* b1   = (const float*)d_in[9];
  const float* W2   = (const float*)d_in[10];
  const float* b2   = (const float*)d_in[11];

  int N  = in_sizes[0] / C;    // 50000
  int E  = in_sizes[1] / 2;    // 800000
  int P  = in_sizes[2] / 2;    // 8192
  int ET = E + N;
  int P2 = 2 * P;
  int nb = (N + SCAN_B - 1) / SCAN_B;   // scan blocks (49)

  float* out       = (float*)d_out;
  float* out_pos   = out;                                  // [2P, 2C] (pos then neg)
  float* out_probs = out + (size_t)P2 * 2 * C;
  float* out_loss  = out_probs + P2;

  char* w = (char*)d_ws;
  size_t NCb2 = (size_t)N * C * 2;                         // bf16 [N,C]
  ushort_t* x_bf  = (ushort_t*)w;  w += NCb2;
  ushort_t* xl_bf = (ushort_t*)w;  w += NCb2;
  ushort_t* xr_bf = (ushort_t*)w;  w += NCb2;
  ushort_t* h1_bf = (ushort_t*)w;  w += NCb2;
  float* h1f = (float*)w;          w += (size_t)N * C * 4;
  ushort_t* pairs_bf = (ushort_t*)w; w += (size_t)P2 * 2 * C * 2;
  float* hid = (float*)w;          w += (size_t)P2 * C * 4;
  ushort_t* wcat = (ushort_t*)w;   w += (size_t)2 * 256 * 128 * 2;
  ushort_t* w1t  = (ushort_t*)w;   w += (size_t)128 * 256 * 2;
  int* deg     = (int*)w;  w += (size_t)N * 4;
  int* row_ptr = (int*)w;  w += (size_t)(N + 1) * 4 + 12;  // keep next aligned
  int* cursor  = (int*)w;  w += (size_t)N * 4;
  int* col     = (int*)w;  w += (size_t)ET * 4;
  int* bsums   = (int*)w;  w += (size_t)(nb + 1) * 4 + 8;
  float* lossacc = (float*)w;

  hipMemsetAsync(deg, 0, (size_t)N * 4, stream);
  hipMemsetAsync(cursor, 0, (size_t)N * 4, stream);
  hipMemsetAsync(lossacc, 0, 4, stream);

  const int tB = 256;
  prep_weights<<<384, tB, 0, stream>>>(Wl, Wr, W1, wcat, w1t);
  convert_x<<<(N * C / 4 + tB - 1) / tB, tB, 0, stream>>>(x, x_bf, N * C / 4);

  hist_kernel<<<(ET + tB - 1) / tB, tB, 0, stream>>>(ei, deg, E, ET);
  scan_block<<<nb, SCAN_B, 0, stream>>>(deg, row_ptr, bsums, N);
  scan_sums<<<1, 64, 0, stream>>>(bsums, nb);
  scan_add<<<(N + SCAN_B - 1) / SCAN_B, SCAN_B, 0, stream>>>(row_ptr, bsums, N, nb);
  scatter_kernel<<<(ET + tB - 1) / tB, tB, 0, stream>>>(ei, row_ptr, cursor, col, E, ET);

  int gblk = (N + 127) / 128;
  const ushort_t* hcur = x_bf;
  for (int l = 0; l < 2; l++) {
    gemm_mfma<<<dim3(gblk, 2), tB, 0, stream>>>(
        hcur, wcat + (size_t)l * 256 * 128, N, C,
        xl_bf, xr_bf, nullptr, nullptr, 0);
    // layer 0: bf16 out (+relu, feeds layer-1 GEMM); layer 1: f32 out (feeds scorer)
    gat_aggregate<<<(N * 64 + tB - 1) / tB, tB, 0, stream>>>(
        xl_bf, xr_bf, row_ptr, col, att + (size_t)l * C, bias + (size_t)l * C,
        (l == 0) ? nullptr : h1f, (l == 0) ? h1_bf : nullptr, N, (l == 0) ? 1 : 0);
    hcur = h1_bf;
  }

  gather_pairs<<<(P2 * 64 + tB - 1) / tB, tB, 0, stream>>>(h1f, tp, fp, (float4*)out_pos, pairs_bf, P2);
  gemm_mfma<<<dim3(P2 / 128, 1), tB, 0, stream>>>(
      pairs_bf, w1t, P2, 2 * C, nullptr, nullptr, hid, b1, 1);
  probs_loss<<<(P2 + tB - 1) / tB, tB, 0, stream>>>(hid, W2, b2, out_probs, lossacc, P2, P);
  finalize_loss<<<1, 1, 0, stream>>>(lossacc, out_loss, P2);
}

// Round 5
// 295.179 us; speedup vs baseline: 2.7252x; 1.1814x over previous
//
#include <hip/hip_runtime.h>
#include <math.h>

#define C 128
#define SCAN_B 1024

typedef unsigned short ushort_t;
typedef short short8 __attribute__((ext_vector_type(8)));
typedef float floatx4 __attribute__((ext_vector_type(4)));

__device__ __forceinline__ ushort_t f2bf(float x) {
  unsigned u = __float_as_uint(x);
  unsigned r = (u + 0x7FFFu + ((u >> 16) & 1u)) >> 16;
  return (ushort_t)r;
}
__device__ __forceinline__ float bfu(unsigned short s) {
  return __uint_as_float(((unsigned)s) << 16);
}

// ---------------- init ----------------

__global__ void init_ws(int* __restrict__ deg, int* __restrict__ cursor,
                        float* __restrict__ lossacc, int n) {
  int i = blockIdx.x * blockDim.x + threadIdx.x;
  if (i < n) { deg[i] = 0; cursor[i] = 0; }
  if (i == 0) lossacc[0] = 0.f;
}

// ---------------- CSR build (sort edges by dst) ----------------

__global__ void hist_kernel(const int* __restrict__ ei, int* __restrict__ deg, int E, int ET) {
  int e = blockIdx.x * blockDim.x + threadIdx.x;
  if (e >= ET) return;
  int d = (e < E) ? ei[E + e] : (e - E);   // self loop dst = node id
  atomicAdd(&deg[d], 1);
}

__global__ void scan_block(const int* __restrict__ deg, int* __restrict__ row_ptr,
                           int* __restrict__ bsums, int n) {
  __shared__ int sh[SCAN_B];
  int tid = threadIdx.x;
  int i = blockIdx.x * SCAN_B + tid;
  int v = (i < n) ? deg[i] : 0;
  sh[tid] = v;
  __syncthreads();
  #pragma unroll
  for (int off = 1; off < SCAN_B; off <<= 1) {
    int t = (tid >= off) ? sh[tid - off] : 0;
    __syncthreads();
    sh[tid] += t;
    __syncthreads();
  }
  if (i < n) row_ptr[i] = sh[tid] - v;          // block-local exclusive
  if (tid == SCAN_B - 1) bsums[blockIdx.x] = sh[tid];
}

__global__ void scan_sums(int* __restrict__ bsums, int nb) {
  int lane = threadIdx.x;
  int v = (lane < nb) ? bsums[lane] : 0;
  int orig = v;
  #pragma unroll
  for (int off = 1; off < 64; off <<= 1) {
    int t = __shfl_up(v, off);
    if (lane >= off) v += t;
  }
  if (lane < nb) bsums[lane] = v - orig;        // exclusive
  if (lane == 63) bsums[nb] = v;                // total
}

__global__ void scan_add(int* __restrict__ row_ptr, const int* __restrict__ bsums, int n, int nb) {
  int i = blockIdx.x * blockDim.x + threadIdx.x;
  if (i < n) row_ptr[i] += bsums[i >> 10];
  if (i == 0) row_ptr[n] = bsums[nb];
}

__global__ void scatter_kernel(const int* __restrict__ ei, const int* __restrict__ row_ptr,
                               int* __restrict__ cursor, int* __restrict__ col, int E, int ET) {
  int e = blockIdx.x * blockDim.x + threadIdx.x;
  if (e >= ET) return;
  int s = (e < E) ? ei[e] : (e - E);
  int d = (e < E) ? ei[E + e] : (e - E);
  int p = atomicAdd(&cursor[d], 1);
  col[row_ptr[d] + p] = s;
}

// ---------------- weight prep: transpose + bf16 ----------------

__global__ void prep_weights(const float* __restrict__ Wl, const float* __restrict__ Wr,
                             const float* __restrict__ W1,
                             ushort_t* __restrict__ wcat, ushort_t* __restrict__ w1t) {
  int idx = blockIdx.x * blockDim.x + threadIdx.x;
  const int NCAT = 2 * 256 * 128;
  if (idx < NCAT) {
    int l = idx >> 15;           // /32768
    int rem = idx & 32767;
    int n = rem >> 7;
    int k = rem & 127;
    float v = (n < 128) ? Wl[l * C * C + k * C + n] : Wr[l * C * C + k * C + (n - 128)];
    wcat[idx] = f2bf(v);
  } else {
    int j = idx - NCAT;          // w1t index
    if (j < 128 * 256) {
      int n = j >> 8;
      int k = j & 255;
      w1t[j] = f2bf(W1[k * C + n]);
    }
  }
}

__global__ void convert_x(const float* __restrict__ x, ushort_t* __restrict__ xb, int total4) {
  int i = blockIdx.x * blockDim.x + threadIdx.x;
  if (i >= total4) return;
  float4 v = ((const float4*)x)[i];
  ushort4 s;
  s.x = f2bf(v.x); s.y = f2bf(v.y); s.z = f2bf(v.z); s.w = f2bf(v.w);
  ((ushort4*)xb)[i] = s;
}

// ---------------- bf16 MFMA GEMM ----------------
// A bf16 [M,K] row-major; Bt bf16 [NN,K] n-major (NN = gridDim.y*128).
// Block (bx,by): rows bx*128..+128, Bt rows by*128..+128.
// Output: if outf: f32 [M,128] (+bias,+relu). else bf16 to (by==0 ? outb0 : outb1).

__global__ __launch_bounds__(256) void gemm_mfma(
    const ushort_t* __restrict__ A, const ushort_t* __restrict__ Bt,
    int M, int K,
    ushort_t* __restrict__ outb0, ushort_t* __restrict__ outb1,
    float* __restrict__ outf, const float* __restrict__ bias, int do_relu) {
  int tid = threadIdx.x;
  int wave = tid >> 6, lane = tid & 63;
  int wm = (wave >> 1) * 64, wn = (wave & 1) * 64;
  int m_base = blockIdx.x * 128 + wm;
  int lrow = lane & 15, lkg = lane >> 4;

  floatx4 acc[4][4];
  #pragma unroll
  for (int mi = 0; mi < 4; mi++)
    #pragma unroll
    for (int ni = 0; ni < 4; ni++)
      acc[mi][ni] = (floatx4){0.f, 0.f, 0.f, 0.f};

  const int ksteps = K >> 5;
  for (int ks = 0; ks < ksteps; ks++) {
    int koff = ks * 32 + lkg * 8;
    short8 af[4], bfr[4];
    #pragma unroll
    for (int mi = 0; mi < 4; mi++) {
      int gm = m_base + mi * 16 + lrow;
      gm = (gm < M) ? gm : (M - 1);
      af[mi] = *(const short8*)&A[(size_t)gm * K + koff];
    }
    #pragma unroll
    for (int ni = 0; ni < 4; ni++) {
      int gn = blockIdx.y * 128 + wn + ni * 16 + lrow;
      bfr[ni] = *(const short8*)&Bt[(size_t)gn * K + koff];
    }
    #pragma unroll
    for (int mi = 0; mi < 4; mi++)
      #pragma unroll
      for (int ni = 0; ni < 4; ni++)
        acc[mi][ni] = __builtin_amdgcn_mfma_f32_16x16x32_bf16(af[mi], bfr[ni], acc[mi][ni], 0, 0, 0);
  }

  ushort_t* outb = (blockIdx.y == 0) ? outb0 : outb1;
  #pragma unroll
  for (int mi = 0; mi < 4; mi++) {
    #pragma unroll
    for (int r = 0; r < 4; r++) {
      int gm = m_base + mi * 16 + lkg * 4 + r;
      if (gm >= M) continue;
      #pragma unroll
      for (int ni = 0; ni < 4; ni++) {
        int nl = wn + ni * 16 + lrow;         // 0..127 within this by's output
        float v = acc[mi][ni][r];
        if (outf) {
          if (bias) v += bias[nl];
          if (do_relu) v = fmaxf(v, 0.f);
          outf[(size_t)gm * 128 + nl] = v;
        } else {
          outb[(size_t)gm * 128 + nl] = f2bf(v);
        }
      }
    }
  }
}

// ---------------- GATv2 edge softmax + aggregation ----------------
// One wave per dst node; 4 groups of 16 lanes, each group one edge/iter,
// 8 channels per lane (16 lanes x 8 = 128). One-pass softmax (exact ratio).

__global__ void gat_aggregate(const ushort_t* __restrict__ xl, const ushort_t* __restrict__ xr,
                              const int* __restrict__ row_ptr, const int* __restrict__ col,
                              const float* __restrict__ att, const float* __restrict__ bias,
                              float* __restrict__ houtf, ushort_t* __restrict__ houtb,
                              int n, int do_relu) {
  int wid = (int)((blockIdx.x * (size_t)blockDim.x + threadIdx.x) >> 6);
  int lane = threadIdx.x & 63;
  if (wid >= n) return;
  int g = lane >> 4, p = lane & 15;
  int c0 = p * 8;
  const size_t i = wid;

  short8 xrv = *(const short8*)&xr[i * C + c0];
  float xri[8], av[8];
  #pragma unroll
  for (int c = 0; c < 8; c++) xri[c] = bfu((unsigned short)xrv[c]);
  float4 a0 = *(const float4*)&att[c0];
  float4 a1 = *(const float4*)&att[c0 + 4];
  av[0]=a0.x; av[1]=a0.y; av[2]=a0.z; av[3]=a0.w;
  av[4]=a1.x; av[5]=a1.y; av[6]=a1.z; av[7]=a1.w;

  int beg = row_ptr[wid], end = row_ptr[wid + 1];
  float denom = 0.f;
  float acc[8];
  #pragma unroll
  for (int c = 0; c < 8; c++) acc[c] = 0.f;

  for (int base = beg; base < end; base += 4) {
    int eidx = base + g;
    bool act = eidx < end;
    int j = col[act ? eidx : beg];
    short8 xlv = *(const short8*)&xl[(size_t)j * C + c0];
    float xlf[8];
    #pragma unroll
    for (int c = 0; c < 8; c++) xlf[c] = bfu((unsigned short)xlv[c]);
    float part = 0.f;
    #pragma unroll
    for (int c = 0; c < 8; c++) {
      float z = xlf[c] + xri[c];
      z = fmaxf(z, 0.2f * z);           // leaky_relu
      part = fmaf(z, av[c], part);
    }
    // reduce within each 16-lane group (4 groups reduce in the same instrs)
    #pragma unroll
    for (int off = 1; off <= 8; off <<= 1)
      part += __shfl_xor(part, off);
    float pe = act ? __expf(part) : 0.f;
    denom += pe;
    #pragma unroll
    for (int c = 0; c < 8; c++) acc[c] = fmaf(pe, xlf[c], acc[c]);
  }

  // combine the 4 groups
  #pragma unroll
  for (int off = 16; off <= 32; off <<= 1) {
    denom += __shfl_xor(denom, off);
    #pragma unroll
    for (int c = 0; c < 8; c++) acc[c] += __shfl_xor(acc[c], off);
  }

  if (g == 0) {
    float inv = 1.f / denom;            // degree >= 1 via self loop
    float4 b0 = *(const float4*)&bias[c0];
    float4 b1 = *(const float4*)&bias[c0 + 4];
    float o[8];
    o[0] = acc[0]*inv + b0.x; o[1] = acc[1]*inv + b0.y;
    o[2] = acc[2]*inv + b0.z; o[3] = acc[3]*inv + b0.w;
    o[4] = acc[4]*inv + b1.x; o[5] = acc[5]*inv + b1.y;
    o[6] = acc[6]*inv + b1.z; o[7] = acc[7]*inv + b1.w;
    if (do_relu) {
      #pragma unroll
      for (int c = 0; c < 8; c++) o[c] = fmaxf(o[c], 0.f);
    }
    if (houtf) {
      *(float4*)&houtf[i * C + c0]     = make_float4(o[0], o[1], o[2], o[3]);
      *(float4*)&houtf[i * C + c0 + 4] = make_float4(o[4], o[5], o[6], o[7]);
    } else {
      short8 s;
      #pragma unroll
      for (int c = 0; c < 8; c++) s[c] = (short)f2bf(o[c]);
      *(short8*)&houtb[i * C + c0] = s;
    }
  }
}

// ---------------- scorer ----------------

__global__ void gather_pairs(const float* __restrict__ h, const int* __restrict__ tp,
                             const int* __restrict__ fp, float4* __restrict__ out,
                             ushort_t* __restrict__ outbf, int P2) {
  int idx = blockIdx.x * blockDim.x + threadIdx.x;   // float4 index over [2P][256/4]
  if (idx >= P2 * 64) return;
  int r = idx >> 6, c4 = idx & 63;
  int half = P2 >> 1;
  const int* pairs = (r < half) ? tp : fp;
  int rr = (r < half) ? r : r - half;
  int node = pairs[rr * 2 + (c4 >= 32 ? 1 : 0)];
  float4 v = *(const float4*)&h[(size_t)node * C + (c4 & 31) * 4];
  out[idx] = v;
  ushort4 s;
  s.x = f2bf(v.x); s.y = f2bf(v.y); s.z = f2bf(v.z); s.w = f2bf(v.w);
  *(ushort4*)&outbf[(size_t)idx * 4] = s;
}

__global__ __launch_bounds__(256) void probs_loss(
    const float* __restrict__ hid, const float* __restrict__ W2,
    const float* __restrict__ b2, float* __restrict__ probs_out,
    float* __restrict__ lossacc, int rows, int P) {
  __shared__ float red[256];
  int tid = threadIdx.x;
  int r = blockIdx.x * blockDim.x + tid;
  float term = 0.f;
  if (r < rows) {
    const float4* hp = (const float4*)&hid[(size_t)r * C];
    const float4* wp = (const float4*)W2;
    float s = 0.f;
    #pragma unroll
    for (int i = 0; i < 32; i++) {
      float4 h4 = hp[i], w4 = wp[i];
      s += h4.x * w4.x + h4.y * w4.y + h4.z * w4.z + h4.w * w4.w;
    }
    s += b2[0];
    float p = 1.f / (1.f + expf(-s));
    probs_out[r] = p;
    float pcl = fminf(fmaxf(p, 1e-7f), 1.f - 1e-7f);
    term = (r < P) ? logf(pcl) : log1pf(-pcl);
  }
  red[tid] = term;
  __syncthreads();
  #pragma unroll
  for (int off = 128; off >= 1; off >>= 1) {
    if (tid < off) red[tid] += red[tid + off];
    __syncthreads();
  }
  if (tid == 0) atomicAdd(lossacc, red[0]);
}

__global__ void finalize_loss(const float* __restrict__ lossacc, float* __restrict__ out, int rows) {
  out[0] = -lossacc[0] / (float)rows;
}

// ---------------- launch ----------------

extern "C" void kernel_launch(void* const* d_in, const int* in_sizes, int n_in,
                              void* d_out, int out_size, void* d_ws, size_t ws_size,
                              hipStream_t stream) {
  const float* x    = (const float*)d_in[0];
  const int*   ei   = (const int*)d_in[1];
  const int*   tp   = (const int*)d_in[2];
  const int*   fp   = (const int*)d_in[3];
  const float* Wl   = (const float*)d_in[4];
  const float* Wr   = (const float*)d_in[5];
  const float* att  = (const float*)d_in[6];
  const float* bias = (const float*)d_in[7];
  const float* W1   = (const float*)d_in[8];
  const float* b1   = (const float*)d_in[9];
  const float* W2   = (const float*)d_in[10];
  const float* b2   = (const float*)d_in[11];

  int N  = in_sizes[0] / C;    // 50000
  int E  = in_sizes[1] / 2;    // 800000
  int P  = in_sizes[2] / 2;    // 8192
  int ET = E + N;
  int P2 = 2 * P;
  int nb = (N + SCAN_B - 1) / SCAN_B;   // scan blocks (49)

  float* out       = (float*)d_out;
  float* out_pos   = out;                                  // [2P, 2C] (pos then neg)
  float* out_probs = out + (size_t)P2 * 2 * C;
  float* out_loss  = out_probs + P2;

  char* w = (char*)d_ws;
  size_t NCb2 = (size_t)N * C * 2;                         // bf16 [N,C]
  ushort_t* x_bf  = (ushort_t*)w;  w += NCb2;
  ushort_t* xl_bf = (ushort_t*)w;  w += NCb2;
  ushort_t* xr_bf = (ushort_t*)w;  w += NCb2;
  ushort_t* h1_bf = (ushort_t*)w;  w += NCb2;
  float* h1f = (float*)w;          w += (size_t)N * C * 4;
  ushort_t* pairs_bf = (ushort_t*)w; w += (size_t)P2 * 2 * C * 2;
  float* hid = (float*)w;          w += (size_t)P2 * C * 4;
  ushort_t* wcat = (ushort_t*)w;   w += (size_t)2 * 256 * 128 * 2;
  ushort_t* w1t  = (ushort_t*)w;   w += (size_t)128 * 256 * 2;
  int* deg     = (int*)w;  w += (size_t)N * 4;
  int* row_ptr = (int*)w;  w += (size_t)(N + 1) * 4 + 12;  // keep next aligned
  int* cursor  = (int*)w;  w += (size_t)N * 4;
  int* col     = (int*)w;  w += (size_t)ET * 4;
  int* bsums   = (int*)w;  w += (size_t)(nb + 1) * 4 + 8;
  float* lossacc = (float*)w;

  const int tB = 256;
  init_ws<<<(N + tB - 1) / tB, tB, 0, stream>>>(deg, cursor, lossacc, N);
  prep_weights<<<384, tB, 0, stream>>>(Wl, Wr, W1, wcat, w1t);
  convert_x<<<(N * C / 4 + tB - 1) / tB, tB, 0, stream>>>(x, x_bf, N * C / 4);

  hist_kernel<<<(ET + tB - 1) / tB, tB, 0, stream>>>(ei, deg, E, ET);
  scan_block<<<nb, SCAN_B, 0, stream>>>(deg, row_ptr, bsums, N);
  scan_sums<<<1, 64, 0, stream>>>(bsums, nb);
  scan_add<<<(N + SCAN_B - 1) / SCAN_B, SCAN_B, 0, stream>>>(row_ptr, bsums, N, nb);
  scatter_kernel<<<(ET + tB - 1) / tB, tB, 0, stream>>>(ei, row_ptr, cursor, col, E, ET);

  int gblk = (N + 127) / 128;
  const ushort_t* hcur = x_bf;
  for (int l = 0; l < 2; l++) {
    gemm_mfma<<<dim3(gblk, 2), tB, 0, stream>>>(
        hcur, wcat + (size_t)l * 256 * 128, N, C,
        xl_bf, xr_bf, nullptr, nullptr, 0);
    // layer 0: bf16 out (+relu, feeds layer-1 GEMM); layer 1: f32 out (feeds scorer)
    gat_aggregate<<<(N * 64 + tB - 1) / tB, tB, 0, stream>>>(
        xl_bf, xr_bf, row_ptr, col, att + (size_t)l * C, bias + (size_t)l * C,
        (l == 0) ? nullptr : h1f, (l == 0) ? h1_bf : nullptr, N, (l == 0) ? 1 : 0);
    hcur = h1_bf;
  }

  gather_pairs<<<(P2 * 64 + tB - 1) / tB, tB, 0, stream>>>(h1f, tp, fp, (float4*)out_pos, pairs_bf, P2);
  gemm_mfma<<<dim3(P2 / 128, 1), tB, 0, stream>>>(
      pairs_bf, w1t, P2, 2 * C, nullptr, nullptr, hid, b1, 1);
  probs_loss<<<(P2 + tB - 1) / tB, tB, 0, stream>>>(hid, W2, b2, out_probs, lossacc, P2, P);
  finalize_loss<<<1, 1, 0, stream>>>(lossacc, out_loss, P2);
}

// Round 6
// 253.397 us; speedup vs baseline: 3.1746x; 1.1649x over previous
//
#include <hip/hip_runtime.h>
#include <math.h>

#define C 128
#define SCAN_B 1024

typedef unsigned short ushort_t;
typedef short short8 __attribute__((ext_vector_type(8)));
typedef float floatx4 __attribute__((ext_vector_type(4)));
typedef float fx2 __attribute__((ext_vector_type(2)));

__device__ __forceinline__ ushort_t f2bf(float x) {
  unsigned u = __float_as_uint(x);
  unsigned r = (u + 0x7FFFu + ((u >> 16) & 1u)) >> 16;
  return (ushort_t)r;
}
__device__ __forceinline__ fx2 bf2f2(unsigned u) {
  fx2 r;
  r.x = __uint_as_float(u << 16);
  r.y = __uint_as_float(u & 0xFFFF0000u);
  return r;
}

// ---------------- init ----------------

__global__ void init_ws(int* __restrict__ deg, float* __restrict__ lossacc, int n) {
  int i = blockIdx.x * blockDim.x + threadIdx.x;
  if (i < n) deg[i] = 0;
  if (i == 0) lossacc[0] = 0.f;
}

// ---------------- CSR build (sort edges by dst) ----------------

__global__ void hist_kernel(const int* __restrict__ ei, int* __restrict__ deg,
                            int* __restrict__ pos, int E, int ET) {
  int e = blockIdx.x * blockDim.x + threadIdx.x;
  if (e >= ET) return;
  int d = (e < E) ? ei[E + e] : (e - E);   // self loop dst = node id
  pos[e] = atomicAdd(&deg[d], 1);
}

__global__ void scan_block(const int* __restrict__ deg, int* __restrict__ row_ptr,
                           int* __restrict__ bsums, int n) {
  __shared__ int sh[SCAN_B];
  int tid = threadIdx.x;
  int i = blockIdx.x * SCAN_B + tid;
  int v = (i < n) ? deg[i] : 0;
  sh[tid] = v;
  __syncthreads();
  #pragma unroll
  for (int off = 1; off < SCAN_B; off <<= 1) {
    int t = (tid >= off) ? sh[tid - off] : 0;
    __syncthreads();
    sh[tid] += t;
    __syncthreads();
  }
  if (i < n) row_ptr[i] = sh[tid] - v;          // block-local exclusive
  if (tid == SCAN_B - 1) bsums[blockIdx.x] = sh[tid];
}

__global__ void scan_sums(int* __restrict__ bsums, int nb) {
  int lane = threadIdx.x;
  int v = (lane < nb) ? bsums[lane] : 0;
  int orig = v;
  #pragma unroll
  for (int off = 1; off < 64; off <<= 1) {
    int t = __shfl_up(v, off);
    if (lane >= off) v += t;
  }
  if (lane < nb) bsums[lane] = v - orig;        // exclusive
  if (lane == 63) bsums[nb] = v;                // total
}

__global__ void scan_add(int* __restrict__ row_ptr, const int* __restrict__ bsums, int n, int nb) {
  int i = blockIdx.x * blockDim.x + threadIdx.x;
  if (i < n) row_ptr[i] += bsums[i >> 10];
  if (i == 0) row_ptr[n] = bsums[nb];
}

// no atomics: position precomputed by hist_kernel
__global__ void scatter_kernel(const int* __restrict__ ei, const int* __restrict__ row_ptr,
                               const int* __restrict__ pos, int* __restrict__ col, int E, int ET) {
  int e = blockIdx.x * blockDim.x + threadIdx.x;
  if (e >= ET) return;
  int s = (e < E) ? ei[e] : (e - E);
  int d = (e < E) ? ei[E + e] : (e - E);
  col[row_ptr[d] + pos[e]] = s;
}

// ---------------- weight prep: transpose + bf16 ----------------

__global__ void prep_weights(const float* __restrict__ Wl, const float* __restrict__ Wr,
                             const float* __restrict__ W1,
                             ushort_t* __restrict__ wcat, ushort_t* __restrict__ w1t) {
  int idx = blockIdx.x * blockDim.x + threadIdx.x;
  const int NCAT = 2 * 256 * 128;
  if (idx < NCAT) {
    int l = idx >> 15;           // /32768
    int rem = idx & 32767;
    int n = rem >> 7;
    int k = rem & 127;
    float v = (n < 128) ? Wl[l * C * C + k * C + n] : Wr[l * C * C + k * C + (n - 128)];
    wcat[idx] = f2bf(v);
  } else {
    int j = idx - NCAT;          // w1t index
    if (j < 128 * 256) {
      int n = j >> 8;
      int k = j & 255;
      w1t[j] = f2bf(W1[k * C + n]);
    }
  }
}

__global__ void convert_x(const float* __restrict__ x, ushort_t* __restrict__ xb, int total4) {
  int i = blockIdx.x * blockDim.x + threadIdx.x;
  if (i >= total4) return;
  float4 v = ((const float4*)x)[i];
  ushort4 s;
  s.x = f2bf(v.x); s.y = f2bf(v.y); s.z = f2bf(v.z); s.w = f2bf(v.w);
  ((ushort4*)xb)[i] = s;
}

// ---------------- bf16 MFMA GEMM ----------------

__global__ __launch_bounds__(256) void gemm_mfma(
    const ushort_t* __restrict__ A, const ushort_t* __restrict__ Bt,
    int M, int K,
    ushort_t* __restrict__ outb0, ushort_t* __restrict__ outb1,
    float* __restrict__ outf, const float* __restrict__ bias, int do_relu) {
  int tid = threadIdx.x;
  int wave = tid >> 6, lane = tid & 63;
  int wm = (wave >> 1) * 64, wn = (wave & 1) * 64;
  int m_base = blockIdx.x * 128 + wm;
  int lrow = lane & 15, lkg = lane >> 4;

  floatx4 acc[4][4];
  #pragma unroll
  for (int mi = 0; mi < 4; mi++)
    #pragma unroll
    for (int ni = 0; ni < 4; ni++)
      acc[mi][ni] = (floatx4){0.f, 0.f, 0.f, 0.f};

  const int ksteps = K >> 5;
  for (int ks = 0; ks < ksteps; ks++) {
    int koff = ks * 32 + lkg * 8;
    short8 af[4], bfr[4];
    #pragma unroll
    for (int mi = 0; mi < 4; mi++) {
      int gm = m_base + mi * 16 + lrow;
      gm = (gm < M) ? gm : (M - 1);
      af[mi] = *(const short8*)&A[(size_t)gm * K + koff];
    }
    #pragma unroll
    for (int ni = 0; ni < 4; ni++) {
      int gn = blockIdx.y * 128 + wn + ni * 16 + lrow;
      bfr[ni] = *(const short8*)&Bt[(size_t)gn * K + koff];
    }
    #pragma unroll
    for (int mi = 0; mi < 4; mi++)
      #pragma unroll
      for (int ni = 0; ni < 4; ni++)
        acc[mi][ni] = __builtin_amdgcn_mfma_f32_16x16x32_bf16(af[mi], bfr[ni], acc[mi][ni], 0, 0, 0);
  }

  ushort_t* outb = (blockIdx.y == 0) ? outb0 : outb1;
  #pragma unroll
  for (int mi = 0; mi < 4; mi++) {
    #pragma unroll
    for (int r = 0; r < 4; r++) {
      int gm = m_base + mi * 16 + lkg * 4 + r;
      if (gm >= M) continue;
      #pragma unroll
      for (int ni = 0; ni < 4; ni++) {
        int nl = wn + ni * 16 + lrow;         // 0..127 within this by's output
        float v = acc[mi][ni][r];
        if (outf) {
          if (bias) v += bias[nl];
          if (do_relu) v = fmaxf(v, 0.f);
          outf[(size_t)gm * 128 + nl] = v;
        } else {
          outb[(size_t)gm * 128 + nl] = f2bf(v);
        }
      }
    }
  }
}

// ---------------- GATv2 edge softmax + aggregation ----------------
// One wave per dst node; 4 groups of 16 lanes; each group handles 2 edges
// per iteration (ILP), 8 channels per lane as packed float2 (v_pk_* f32).

__global__ void gat_aggregate(const ushort_t* __restrict__ xl, const ushort_t* __restrict__ xr,
                              const int* __restrict__ row_ptr, const int* __restrict__ col,
                              const float* __restrict__ att, const float* __restrict__ bias,
                              float* __restrict__ houtf, ushort_t* __restrict__ houtb,
                              int n, int do_relu) {
  int wid = (int)((blockIdx.x * (size_t)blockDim.x + threadIdx.x) >> 6);
  int lane = threadIdx.x & 63;
  if (wid >= n) return;
  int g = lane >> 4, p = lane & 15;
  int c0 = p * 8;
  const size_t i = wid;

  fx2 xri[4], av[4];
  {
    uint4 ur = *(const uint4*)&xr[i * C + c0];
    xri[0] = bf2f2(ur.x); xri[1] = bf2f2(ur.y);
    xri[2] = bf2f2(ur.z); xri[3] = bf2f2(ur.w);
    float4 a0 = *(const float4*)&att[c0];
    float4 a1 = *(const float4*)&att[c0 + 4];
    av[0] = (fx2){a0.x, a0.y}; av[1] = (fx2){a0.z, a0.w};
    av[2] = (fx2){a1.x, a1.y}; av[3] = (fx2){a1.z, a1.w};
  }

  int beg = row_ptr[wid], end = row_ptr[wid + 1];
  float denom = 0.f;
  fx2 acc[4];
  #pragma unroll
  for (int q = 0; q < 4; q++) acc[q] = (fx2){0.f, 0.f};

  for (int base = beg; base < end; base += 8) {
    int e0 = base + g;
    int e1 = e0 + 4;
    bool a0 = e0 < end, a1 = e1 < end;
    int j0 = col[a0 ? e0 : beg];
    int j1 = col[a1 ? e1 : beg];
    uint4 r0 = *(const uint4*)&xl[((size_t)j0 << 7) + c0];
    uint4 r1 = *(const uint4*)&xl[((size_t)j1 << 7) + c0];
    fx2 x0[4], x1[4];
    x0[0] = bf2f2(r0.x); x0[1] = bf2f2(r0.y); x0[2] = bf2f2(r0.z); x0[3] = bf2f2(r0.w);
    x1[0] = bf2f2(r1.x); x1[1] = bf2f2(r1.y); x1[2] = bf2f2(r1.z); x1[3] = bf2f2(r1.w);

    fx2 d0 = (fx2){0.f, 0.f}, d1 = (fx2){0.f, 0.f};
    #pragma unroll
    for (int q = 0; q < 4; q++) {
      fx2 z0 = x0[q] + xri[q];
      fx2 z1 = x1[q] + xri[q];
      z0 = __builtin_elementwise_max(z0, z0 * 0.2f);
      z1 = __builtin_elementwise_max(z1, z1 * 0.2f);
      d0 = __builtin_elementwise_fma(z0, av[q], d0);
      d1 = __builtin_elementwise_fma(z1, av[q], d1);
    }
    float p0 = d0.x + d0.y;
    float p1 = d1.x + d1.y;
    #pragma unroll
    for (int off = 1; off <= 8; off <<= 1) {
      p0 += __shfl_xor(p0, off);
      p1 += __shfl_xor(p1, off);
    }
    float pe0 = a0 ? __expf(p0) : 0.f;
    float pe1 = a1 ? __expf(p1) : 0.f;
    denom += pe0 + pe1;
    fx2 v0 = (fx2){pe0, pe0}, v1 = (fx2){pe1, pe1};
    #pragma unroll
    for (int q = 0; q < 4; q++) {
      acc[q] = __builtin_elementwise_fma(v0, x0[q], acc[q]);
      acc[q] = __builtin_elementwise_fma(v1, x1[q], acc[q]);
    }
  }

  // combine the 4 groups
  #pragma unroll
  for (int off = 16; off <= 32; off <<= 1) {
    denom += __shfl_xor(denom, off);
    #pragma unroll
    for (int q = 0; q < 4; q++) {
      acc[q].x += __shfl_xor(acc[q].x, off);
      acc[q].y += __shfl_xor(acc[q].y, off);
    }
  }

  if (g == 0) {
    float inv = 1.f / denom;            // degree >= 1 via self loop
    float4 b0 = *(const float4*)&bias[c0];
    float4 b1 = *(const float4*)&bias[c0 + 4];
    float o[8];
    o[0] = acc[0].x*inv + b0.x; o[1] = acc[0].y*inv + b0.y;
    o[2] = acc[1].x*inv + b0.z; o[3] = acc[1].y*inv + b0.w;
    o[4] = acc[2].x*inv + b1.x; o[5] = acc[2].y*inv + b1.y;
    o[6] = acc[3].x*inv + b1.z; o[7] = acc[3].y*inv + b1.w;
    if (do_relu) {
      #pragma unroll
      for (int c = 0; c < 8; c++) o[c] = fmaxf(o[c], 0.f);
    }
    if (houtf) {
      *(float4*)&houtf[i * C + c0]     = make_float4(o[0], o[1], o[2], o[3]);
      *(float4*)&houtf[i * C + c0 + 4] = make_float4(o[4], o[5], o[6], o[7]);
    } else {
      short8 s;
      #pragma unroll
      for (int c = 0; c < 8; c++) s[c] = (short)f2bf(o[c]);
      *(short8*)&houtb[i * C + c0] = s;
    }
  }
}

// ---------------- scorer ----------------

__global__ void gather_pairs(const float* __restrict__ h, const int* __restrict__ tp,
                             const int* __restrict__ fp, float4* __restrict__ out,
                             ushort_t* __restrict__ outbf, int P2) {
  int idx = blockIdx.x * blockDim.x + threadIdx.x;   // float4 index over [2P][256/4]
  if (idx >= P2 * 64) return;
  int r = idx >> 6, c4 = idx & 63;
  int half = P2 >> 1;
  const int* pairs = (r < half) ? tp : fp;
  int rr = (r < half) ? r : r - half;
  int node = pairs[rr * 2 + (c4 >= 32 ? 1 : 0)];
  float4 v = *(const float4*)&h[(size_t)node * C + (c4 & 31) * 4];
  out[idx] = v;
  ushort4 s;
  s.x = f2bf(v.x); s.y = f2bf(v.y); s.z = f2bf(v.z); s.w = f2bf(v.w);
  *(ushort4*)&outbf[(size_t)idx * 4] = s;
}

__global__ __launch_bounds__(256) void probs_loss(
    const float* __restrict__ hid, const float* __restrict__ W2,
    const float* __restrict__ b2, float* __restrict__ probs_out,
    float* __restrict__ lossacc, int rows, int P) {
  __shared__ float red[256];
  int tid = threadIdx.x;
  int r = blockIdx.x * blockDim.x + tid;
  float term = 0.f;
  if (r < rows) {
    const float4* hp = (const float4*)&hid[(size_t)r * C];
    const float4* wp = (const float4*)W2;
    float s = 0.f;
    #pragma unroll
    for (int i = 0; i < 32; i++) {
      float4 h4 = hp[i], w4 = wp[i];
      s += h4.x * w4.x + h4.y * w4.y + h4.z * w4.z + h4.w * w4.w;
    }
    s += b2[0];
    float p = 1.f / (1.f + expf(-s));
    probs_out[r] = p;
    float pcl = fminf(fmaxf(p, 1e-7f), 1.f - 1e-7f);
    term = (r < P) ? logf(pcl) : log1pf(-pcl);
  }
  red[tid] = term;
  __syncthreads();
  #pragma unroll
  for (int off = 128; off >= 1; off >>= 1) {
    if (tid < off) red[tid] += red[tid + off];
    __syncthreads();
  }
  if (tid == 0) atomicAdd(lossacc, red[0]);
}

__global__ void finalize_loss(const float* __restrict__ lossacc, float* __restrict__ out, int rows) {
  out[0] = -lossacc[0] / (float)rows;
}

// ---------------- launch ----------------

extern "C" void kernel_launch(void* const* d_in, const int* in_sizes, int n_in,
                              void* d_out, int out_size, void* d_ws, size_t ws_size,
                              hipStream_t stream) {
  const float* x    = (const float*)d_in[0];
  const int*   ei   = (const int*)d_in[1];
  const int*   tp   = (const int*)d_in[2];
  const int*   fp   = (const int*)d_in[3];
  const float* Wl   = (const float*)d_in[4];
  const float* Wr   = (const float*)d_in[5];
  const float* att  = (const float*)d_in[6];
  const float* bias = (const float*)d_in[7];
  const float* W1   = (const float*)d_in[8];
  const float* b1   = (const float*)d_in[9];
  const float* W2   = (const float*)d_in[10];
  const float* b2   = (const float*)d_in[11];

  int N  = in_sizes[0] / C;    // 50000
  int E  = in_sizes[1] / 2;    // 800000
  int P  = in_sizes[2] / 2;    // 8192
  int ET = E + N;
  int P2 = 2 * P;
  int nb = (N + SCAN_B - 1) / SCAN_B;   // scan blocks (49)

  float* out       = (float*)d_out;
  float* out_pos   = out;                                  // [2P, 2C] (pos then neg)
  float* out_probs = out + (size_t)P2 * 2 * C;
  float* out_loss  = out_probs + P2;

  char* w = (char*)d_ws;
  size_t NCb2 = (size_t)N * C * 2;                         // bf16 [N,C]
  ushort_t* x_bf  = (ushort_t*)w;  w += NCb2;
  ushort_t* xl_bf = (ushort_t*)w;  w += NCb2;
  ushort_t* xr_bf = (ushort_t*)w;  w += NCb2;
  ushort_t* h1_bf = (ushort_t*)w;  w += NCb2;
  float* h1f = (float*)w;          w += (size_t)N * C * 4;
  ushort_t* pairs_bf = (ushort_t*)w; w += (size_t)P2 * 2 * C * 2;
  float* hid = (float*)w;          w += (size_t)P2 * C * 4;
  ushort_t* wcat = (ushort_t*)w;   w += (size_t)2 * 256 * 128 * 2;
  ushort_t* w1t  = (ushort_t*)w;   w += (size_t)128 * 256 * 2;
  int* deg     = (int*)w;  w += (size_t)N * 4;
  int* row_ptr = (int*)w;  w += (size_t)(N + 1) * 4 + 12;  // keep next aligned
  int* pos     = (int*)w;  w += (size_t)ET * 4;
  int* col     = (int*)w;  w += (size_t)ET * 4;
  int* bsums   = (int*)w;  w += (size_t)(nb + 1) * 4 + 8;
  float* lossacc = (float*)w;

  const int tB = 256;
  init_ws<<<(N + tB - 1) / tB, tB, 0, stream>>>(deg, lossacc, N);
  prep_weights<<<384, tB, 0, stream>>>(Wl, Wr, W1, wcat, w1t);
  convert_x<<<(N * C / 4 + tB - 1) / tB, tB, 0, stream>>>(x, x_bf, N * C / 4);

  hist_kernel<<<(ET + tB - 1) / tB, tB, 0, stream>>>(ei, deg, pos, E, ET);
  scan_block<<<nb, SCAN_B, 0, stream>>>(deg, row_ptr, bsums, N);
  scan_sums<<<1, 64, 0, stream>>>(bsums, nb);
  scan_add<<<(N + SCAN_B - 1) / SCAN_B, SCAN_B, 0, stream>>>(row_ptr, bsums, N, nb);
  scatter_kernel<<<(ET + tB - 1) / tB, tB, 0, stream>>>(ei, row_ptr, pos, col, E, ET);

  int gblk = (N + 127) / 128;
  const ushort_t* hcur = x_bf;
  for (int l = 0; l < 2; l++) {
    gemm_mfma<<<dim3(gblk, 2), tB, 0, stream>>>(
        hcur, wcat + (size_t)l * 256 * 128, N, C,
        xl_bf, xr_bf, nullptr, nullptr, 0);
    // layer 0: bf16 out (+relu, feeds layer-1 GEMM); layer 1: f32 out (feeds scorer)
    gat_aggregate<<<(N * 64 + tB - 1) / tB, tB, 0, stream>>>(
        xl_bf, xr_bf, row_ptr, col, att + (size_t)l * C, bias + (size_t)l * C,
        (l == 0) ? nullptr : h1f, (l == 0) ? h1_bf : nullptr, N, (l == 0) ? 1 : 0);
    hcur = h1_bf;
  }

  gather_pairs<<<(P2 * 64 + tB - 1) / tB, tB, 0, stream>>>(h1f, tp, fp, (float4*)out_pos, pairs_bf, P2);
  gemm_mfma<<<dim3(P2 / 128, 1), tB, 0, stream>>>(
      pairs_bf, w1t, P2, 2 * C, nullptr, nullptr, hid, b1, 1);
  probs_loss<<<(P2 + tB - 1) / tB, tB, 0, stream>>>(hid, W2, b2, out_probs, lossacc, P2, P);
  finalize_loss<<<1, 1, 0, stream>>>(lossacc, out_loss, P2);
}